// Round 1
// baseline (349.102 us; speedup 1.0000x reference)
//
#include <hip/hip_runtime.h>
#include <math.h>

#define NN 4096
#define DD 256
#define KK 2048
#define NW 64   // u64 words per bitmask row

// ---------------- column stats (two-pass, fp64, deterministic) ----------------
__global__ void k_colsum_part(const float* __restrict__ h, double* __restrict__ part) {
    int d = threadIdx.x;           // 0..255
    int b = blockIdx.x;            // 0..31
    double acc = 0.0;
    int r0 = b * (NN / 32);
    for (int r = r0; r < r0 + NN / 32; ++r) acc += (double)h[(size_t)r * DD + d];
    part[b * DD + d] = acc;
}

__global__ void k_colmean(const double* __restrict__ part, double* __restrict__ mu) {
    int d = threadIdx.x;
    double acc = 0.0;
    for (int b = 0; b < 32; ++b) acc += part[b * DD + d];
    mu[d] = acc / (double)NN;
}

__global__ void k_colvar_part(const float* __restrict__ h, const double* __restrict__ mu,
                              double* __restrict__ part) {
    int d = threadIdx.x;
    int b = blockIdx.x;
    double m = mu[d], acc = 0.0;
    int r0 = b * (NN / 32);
    for (int r = r0; r < r0 + NN / 32; ++r) {
        double t = (double)h[(size_t)r * DD + d] - m;
        acc += t * t;
    }
    part[b * DD + d] = acc;
}

__global__ void k_colrstd(const double* __restrict__ part, double* __restrict__ rstd) {
    int d = threadIdx.x;
    double acc = 0.0;
    for (int b = 0; b < 32; ++b) acc += part[b * DD + d];
    double var = acc / (double)NN;
    rstd[d] = 1.0 / sqrt(var + 1e-5);
}

// ---------------- normalized h (fp32 copy for output path) ----------------
__global__ void k_norm(const float* __restrict__ h, const double* __restrict__ mu,
                       const double* __restrict__ rstd, const float* __restrict__ gamma,
                       const float* __restrict__ beta, float* __restrict__ hn) {
    int i = blockIdx.x * 256 + threadIdx.x;   // grid = NN*DD/256
    int d = i & (DD - 1);
    hn[i] = (float)(((double)h[i] - mu[d]) * rstd[d] * (double)gamma[d] + (double)beta[d]);
}

// ---------------- pf dot product: z = h_norm . w + b (fp64), one wave/row ----------------
__global__ void k_zpf(const float* __restrict__ h, const double* __restrict__ mu,
                      const double* __restrict__ rstd, const float* __restrict__ gamma,
                      const float* __restrict__ beta, const float* __restrict__ w,
                      const float* __restrict__ bp, double* __restrict__ zpf) {
    int r = blockIdx.x;
    int l = threadIdx.x;   // 64
    double acc = 0.0;
    for (int d = l; d < DD; d += 64) {
        double hn = ((double)h[(size_t)r * DD + d] - mu[d]) * rstd[d] * (double)gamma[d] + (double)beta[d];
        acc += hn * (double)w[d];
    }
    for (int off = 32; off > 0; off >>= 1) acc += __shfl_down(acc, off);
    if (l == 0) zpf[r] = acc + (double)bp[0];
}

// ---------------- bitmask of g rows + degree ----------------
__global__ void k_bitmask(const float* __restrict__ g, unsigned long long* __restrict__ B,
                          int* __restrict__ degi) {
    int i = blockIdx.x;
    int tid = threadIdx.x;             // 256 = 4 waves
    int w = tid >> 6, l = tid & 63;
    __shared__ int pc[4];
    int local = 0;
    for (int wi = 0; wi < 16; ++wi) {
        int word = wi * 4 + w;
        float v = g[(size_t)i * NN + (size_t)word * 64 + l];
        unsigned long long m = __ballot(v != 0.0f);
        if (l == 0) {
            B[(size_t)i * NW + word] = m;
            local += __popcll(m);
        }
    }
    if (l == 0) pc[w] = local;
    __syncthreads();
    if (tid == 0) degi[i] = pc[0] + pc[1] + pc[2] + pc[3];
}

// ---------------- two-hop bitmask: T[i] = OR_{j in N(i)} B[j] ----------------
__global__ void k_twohop(const unsigned long long* __restrict__ B,
                         unsigned long long* __restrict__ T) {
    int i = blockIdx.x;
    int t = threadIdx.x;   // 64
    unsigned long long acc = 0ull;
    for (int w = 0; w < NW; ++w) {
        unsigned long long word = B[(size_t)i * NW + w];
        while (word) {
            int b = (int)__ffsll((unsigned long long)word) - 1;
            word &= word - 1;
            int j = w * 64 + b;
            acc |= B[(size_t)j * NW + t];
        }
    }
    T[(size_t)i * NW + t] = acc;
}

// ---------------- agg (sparse avg), Z1, Z3 in fp64 ----------------
__global__ void k_agg(const float* __restrict__ h, const double* __restrict__ mu,
                      const double* __restrict__ rstd, const float* __restrict__ gamma,
                      const float* __restrict__ beta, const unsigned long long* __restrict__ B,
                      const int* __restrict__ degi, const float* __restrict__ w,
                      const float* __restrict__ bp, double* __restrict__ Z1,
                      double* __restrict__ Z3) {
    int i = blockIdx.x;
    int t = threadIdx.x;   // 256, t == d
    __shared__ double red[256];
    double mud = mu[t], rsd = rstd[t];
    double gad = (double)gamma[t], bed = (double)beta[t];
    double acc = 0.0;
    for (int wd = 0; wd < NW; ++wd) {
        unsigned long long word = B[(size_t)i * NW + wd];
        while (word) {
            int b = (int)__ffsll((unsigned long long)word) - 1;
            word &= word - 1;
            int j = wd * 64 + b;
            acc += ((double)h[(size_t)j * DD + t] - mud) * rsd * gad + bed;
        }
    }
    double aggd = acc / (double)degi[i];
    double hni = ((double)h[(size_t)i * DD + t] - mud) * rsd * gad + bed;
    double z1t = fabs(hni - aggd);
    double z3t = aggd * (double)w[t];

    red[t] = z1t;
    __syncthreads();
    for (int s = 128; s > 0; s >>= 1) {
        if (t < s) red[t] += red[t + s];
        __syncthreads();
    }
    if (t == 0) Z1[i] = red[0];
    __syncthreads();
    red[t] = z3t;
    __syncthreads();
    for (int s = 128; s > 0; s >>= 1) {
        if (t < s) red[t] += red[t + s];
        __syncthreads();
    }
    if (t == 0) Z3[i] = red[0] + (double)bp[0];
}

// ---------------- softmax over Z3 + final scores (single block, fp64) ----------------
__global__ void k_scores(const double* __restrict__ Z1, const double* __restrict__ Z3,
                         const double* __restrict__ zpf, const int* __restrict__ degi,
                         const float* __restrict__ sigma1, float* __restrict__ scores) {
    __shared__ double red[1024];
    int tid = threadIdx.x;
    double mx = -1e300;
    for (int i = tid; i < NN; i += 1024) mx = fmax(mx, Z3[i]);
    red[tid] = mx;
    __syncthreads();
    for (int s = 512; s > 0; s >>= 1) {
        if (tid < s) red[tid] = fmax(red[tid], red[tid + s]);
        __syncthreads();
    }
    double m = red[0];
    __syncthreads();
    double se = 0.0;
    for (int i = tid; i < NN; i += 1024) se += exp(Z3[i] - m);
    red[tid] = se;
    __syncthreads();
    for (int s = 512; s > 0; s >>= 1) {
        if (tid < s) red[tid] += red[tid + s];
        __syncthreads();
    }
    double sum = red[0];
    double s1 = (double)sigma1[0];
    for (int i = tid; i < NN; i += 1024) {
        double pg = exp(Z3[i] - m) / sum;
        double pl = 1.0 / (1.0 + exp(-(Z1[i] + (double)degi[i])));
        double pt = 1.0 / (1.0 + exp(-(pl + pg)));
        double pf = 1.0 / (1.0 + exp(-zpf[i]));
        scores[i] = (float)(s1 * pt + (1.0 - s1) * pf);
    }
}

// ---------------- top-k via single-block bitonic sort on (score desc, idx asc) ----------------
__global__ void k_topk(const float* __restrict__ scores, int* __restrict__ idx_int,
                       unsigned long long* __restrict__ S, float* __restrict__ out_idx) {
    __shared__ unsigned long long keys[NN];
    __shared__ unsigned long long Sl[NW];
    int tid = threadIdx.x;   // 1024
    for (int i = tid; i < NN; i += 1024) {
        unsigned int b = __float_as_uint(scores[i]);
        unsigned int ka = (b & 0x80000000u) ? ~b : (b ^ 0x80000000u);  // ascending order key
        unsigned int kd = ~ka;                                          // descending
        keys[i] = ((unsigned long long)kd << 32) | (unsigned int)i;
    }
    __syncthreads();
    for (int kk = 2; kk <= NN; kk <<= 1) {
        for (int j = kk >> 1; j > 0; j >>= 1) {
            for (int i = tid; i < NN; i += 1024) {
                int ix = i ^ j;
                if (ix > i) {
                    bool up = ((i & kk) == 0);
                    unsigned long long a = keys[i], c = keys[ix];
                    if ((a > c) == up) { keys[i] = c; keys[ix] = a; }
                }
            }
            __syncthreads();
        }
    }
    if (tid < NW) Sl[tid] = 0ull;
    __syncthreads();
    for (int r = tid; r < KK; r += 1024) {
        unsigned int ii = (unsigned int)(keys[r] & 0xffffffffu);
        idx_int[r] = (int)ii;
        out_idx[r] = (float)ii;
        atomicOr(&Sl[ii >> 6], 1ull << (ii & 63));
    }
    __syncthreads();
    if (tid < NW) S[tid] = Sl[tid];
}

// ---------------- row sums for g_new normalization (note: divides COLUMN c by rowsum of row c) ----
__global__ void k_rowsum(const unsigned long long* __restrict__ T, const int* __restrict__ idx_int,
                         const unsigned long long* __restrict__ S, float* __restrict__ inv_rs) {
    int j = blockIdx.x * 256 + threadIdx.x;   // grid 8
    if (j >= KK) return;
    int r = idx_int[j];
    int c = 0;
    for (int w = 0; w < NW; ++w) c += __popcll(T[(size_t)r * NW + w] & S[w]);
    inv_rs[j] = 1.0f / (float)c;
}

// ---------------- g_new output ----------------
__global__ void k_gnew(const unsigned long long* __restrict__ T, const int* __restrict__ idx_int,
                       const float* __restrict__ inv_rs, float* __restrict__ out) {
    int r = blockIdx.x;
    int tid = threadIdx.x;   // 256
    __shared__ unsigned long long Tl[NW];
    if (tid < NW) Tl[tid] = T[(size_t)idx_int[r] * NW + tid];
    __syncthreads();
    for (int c = tid; c < KK; c += 256) {
        int jc = idx_int[c];
        int bit = (int)((Tl[jc >> 6] >> (jc & 63)) & 1ull);
        out[(size_t)r * KK + c] = bit ? inv_rs[c] : 0.0f;
    }
}

// ---------------- new_h output: sum of score-weighted h_norm rows over two-hop bits ----------------
__global__ void k_newh(const unsigned long long* __restrict__ T, const int* __restrict__ idx_int,
                       const float* __restrict__ scores, const float* __restrict__ hn,
                       float* __restrict__ out) {
    int r = blockIdx.x;
    int t = threadIdx.x;   // 256, t == d
    __shared__ unsigned long long Tl[NW];
    if (t < NW) Tl[t] = T[(size_t)idx_int[r] * NW + t];
    __syncthreads();
    float acc = 0.0f;
    for (int w = 0; w < NW; ++w) {
        unsigned long long word = Tl[w];
        while (word) {
            int b = (int)__ffsll((unsigned long long)word) - 1;
            word &= word - 1;
            int c = w * 64 + b;
            acc = fmaf(scores[c], hn[(size_t)c * DD + t], acc);
        }
    }
    out[(size_t)r * DD + t] = acc;
}

extern "C" void kernel_launch(void* const* d_in, const int* in_sizes, int n_in,
                              void* d_out, int out_size, void* d_ws, size_t ws_size,
                              hipStream_t stream) {
    const float* g      = (const float*)d_in[0];
    const float* h      = (const float*)d_in[1];
    const float* gamma  = (const float*)d_in[2];
    const float* beta   = (const float*)d_in[3];
    const float* w_proj = (const float*)d_in[4];
    const float* b_proj = (const float*)d_in[5];
    const float* sigma1 = (const float*)d_in[6];

    // workspace bump allocator (256-B aligned)
    char* p = (char*)d_ws;
    auto alloc = [&](size_t bytes) -> void* {
        void* q = (void*)p;
        p += (bytes + 255) & ~(size_t)255;
        return q;
    };
    double* mu      = (double*)alloc(DD * 8);
    double* rstd    = (double*)alloc(DD * 8);
    double* part    = (double*)alloc(32 * DD * 8);
    double* zpf     = (double*)alloc(NN * 8);
    double* Z1      = (double*)alloc(NN * 8);
    double* Z3      = (double*)alloc(NN * 8);
    int*    degi    = (int*)alloc(NN * 4);
    float*  scores  = (float*)alloc(NN * 4);
    int*    idx_int = (int*)alloc(KK * 4);
    unsigned long long* S = (unsigned long long*)alloc(NW * 8);
    float*  inv_rs  = (float*)alloc(KK * 4);
    unsigned long long* B = (unsigned long long*)alloc((size_t)NN * NW * 8);
    unsigned long long* T = (unsigned long long*)alloc((size_t)NN * NW * 8);
    float*  hn      = (float*)alloc((size_t)NN * DD * 4);

    float* out_gnew = (float*)d_out;                       // KK*KK
    float* out_newh = out_gnew + (size_t)KK * KK;          // KK*DD
    float* out_idx  = out_newh + (size_t)KK * DD;          // KK

    hipLaunchKernelGGL(k_colsum_part, dim3(32), dim3(256), 0, stream, h, part);
    hipLaunchKernelGGL(k_colmean,     dim3(1),  dim3(256), 0, stream, part, mu);
    hipLaunchKernelGGL(k_colvar_part, dim3(32), dim3(256), 0, stream, h, mu, part);
    hipLaunchKernelGGL(k_colrstd,     dim3(1),  dim3(256), 0, stream, part, rstd);
    hipLaunchKernelGGL(k_norm,        dim3(NN), dim3(256), 0, stream, h, mu, rstd, gamma, beta, hn);
    hipLaunchKernelGGL(k_zpf,         dim3(NN), dim3(64),  0, stream, h, mu, rstd, gamma, beta, w_proj, b_proj, zpf);
    hipLaunchKernelGGL(k_bitmask,     dim3(NN), dim3(256), 0, stream, g, B, degi);
    hipLaunchKernelGGL(k_twohop,      dim3(NN), dim3(64),  0, stream, B, T);
    hipLaunchKernelGGL(k_agg,         dim3(NN), dim3(256), 0, stream, h, mu, rstd, gamma, beta, B, degi, w_proj, b_proj, Z1, Z3);
    hipLaunchKernelGGL(k_scores,      dim3(1),  dim3(1024), 0, stream, Z1, Z3, zpf, degi, sigma1, scores);
    hipLaunchKernelGGL(k_topk,        dim3(1),  dim3(1024), 0, stream, scores, idx_int, S, out_idx);
    hipLaunchKernelGGL(k_rowsum,      dim3(8),  dim3(256), 0, stream, T, idx_int, S, inv_rs);
    hipLaunchKernelGGL(k_gnew,        dim3(KK), dim3(256), 0, stream, T, idx_int, inv_rs, out_gnew);
    hipLaunchKernelGGL(k_newh,        dim3(KK), dim3(256), 0, stream, T, idx_int, scores, hn, out_newh);
}

// Round 2
// 287.918 us; speedup vs baseline: 1.2125x; 1.2125x over previous
//
#include <hip/hip_runtime.h>
#include <math.h>

#define NN 4096
#define DD 256
#define KK 2048
#define NW 64   // u64 words per bitmask row

// ---------------- fused column stats: partial sum + sumsq (fp64) ----------------
// grid 256, block 256. Block b handles rows [16b, 16b+16).
__global__ void k_stats_part(const float* __restrict__ h, double* __restrict__ psum,
                             double* __restrict__ psq) {
    int d = threadIdx.x;
    int b = blockIdx.x;
    int r0 = b * 16;
    double s0=0,s1=0,s2=0,s3=0,q0=0,q1=0,q2=0,q3=0;
    for (int k = 0; k < 16; k += 4) {
        double x0 = (double)h[(size_t)(r0+k+0) * DD + d];
        double x1 = (double)h[(size_t)(r0+k+1) * DD + d];
        double x2 = (double)h[(size_t)(r0+k+2) * DD + d];
        double x3 = (double)h[(size_t)(r0+k+3) * DD + d];
        s0 += x0; q0 += x0*x0;
        s1 += x1; q1 += x1*x1;
        s2 += x2; q2 += x2*x2;
        s3 += x3; q3 += x3*x3;
    }
    psum[b * DD + d] = (s0+s1)+(s2+s3);
    psq [b * DD + d] = (q0+q1)+(q2+q3);
}

// 1 block, 1024 threads: thread = d + 256*q, q in 0..3 each sums 64 partials.
__global__ void k_stats_final(const double* __restrict__ psum, const double* __restrict__ psq,
                              double* __restrict__ mu, double* __restrict__ rstd) {
    __shared__ double rs[4][DD];
    __shared__ double rq[4][DD];
    int t = threadIdx.x;
    int d = t & (DD - 1);
    int q = t >> 8;
    double s0=0,s1=0,q0=0,q1=0;
    int b0 = q * 64;
    for (int k = 0; k < 64; k += 2) {
        s0 += psum[(b0+k)   * DD + d];
        s1 += psum[(b0+k+1) * DD + d];
        q0 += psq [(b0+k)   * DD + d];
        q1 += psq [(b0+k+1) * DD + d];
    }
    rs[q][d] = s0 + s1;
    rq[q][d] = q0 + q1;
    __syncthreads();
    if (q == 0) {
        double S  = (rs[0][d]+rs[1][d]) + (rs[2][d]+rs[3][d]);
        double Q  = (rq[0][d]+rq[1][d]) + (rq[2][d]+rq[3][d]);
        double m  = S / (double)NN;
        double var = Q / (double)NN - m * m;
        mu[d]   = m;
        rstd[d] = 1.0 / sqrt(var + 1e-5);
    }
}

// ---------------- normalized h (fp32) + fused zpf = hn . w + b (fp64) ----------------
// grid NN, block 256 (block = row)
__global__ void k_norm_zpf(const float* __restrict__ h, const double* __restrict__ mu,
                           const double* __restrict__ rstd, const float* __restrict__ gamma,
                           const float* __restrict__ beta, const float* __restrict__ w,
                           const float* __restrict__ bp, float* __restrict__ hn,
                           double* __restrict__ zpf) {
    __shared__ double red[DD];
    int r = blockIdx.x;
    int d = threadIdx.x;
    size_t i = (size_t)r * DD + d;
    double hnd = ((double)h[i] - mu[d]) * rstd[d] * (double)gamma[d] + (double)beta[d];
    hn[i] = (float)hnd;
    red[d] = hnd * (double)w[d];
    __syncthreads();
    for (int s = 128; s > 0; s >>= 1) {
        if (d < s) red[d] += red[d + s];
        __syncthreads();
    }
    if (d == 0) zpf[r] = red[0] + (double)bp[0];
}

// ---------------- bitmask of g rows + degree ----------------
__global__ void k_bitmask(const float* __restrict__ g, unsigned long long* __restrict__ B,
                          int* __restrict__ degi) {
    int i = blockIdx.x;
    int tid = threadIdx.x;             // 256 = 4 waves
    int w = tid >> 6, l = tid & 63;
    __shared__ int pc[4];
    int local = 0;
    for (int wi = 0; wi < 16; ++wi) {
        int word = wi * 4 + w;
        float v = g[(size_t)i * NN + (size_t)word * 64 + l];
        unsigned long long m = __ballot(v != 0.0f);
        if (l == 0) {
            B[(size_t)i * NW + word] = m;
            local += __popcll(m);
        }
    }
    if (l == 0) pc[w] = local;
    __syncthreads();
    if (tid == 0) degi[i] = pc[0] + pc[1] + pc[2] + pc[3];
}

// ---------------- two-hop bitmask: T[i] = OR_{j in N(i)} B[j], 4-wave split ----------------
__global__ void k_twohop(const unsigned long long* __restrict__ B,
                         unsigned long long* __restrict__ T) {
    int i = blockIdx.x;
    int t = threadIdx.x;       // 256
    int w = t >> 6, l = t & 63;
    __shared__ unsigned long long red[4][NW];
    unsigned long long acc = 0ull;
    for (int wd = w * 16; wd < w * 16 + 16; ++wd) {
        unsigned long long word = B[(size_t)i * NW + wd];
        while (word) {
            int b = (int)__ffsll(word) - 1;
            word &= word - 1;
            acc |= B[(size_t)(wd * 64 + b) * NW + l];
        }
    }
    red[w][l] = acc;
    __syncthreads();
    if (t < NW)
        T[(size_t)i * NW + t] = (red[0][t] | red[1][t]) | (red[2][t] | red[3][t]);
}

// ---------------- agg (sparse avg), Z1, Z3 in fp64 — list-based, 4 accumulators ----------------
// mean_j(norm(h_j)) == norm(mean_j(h_j)): inner loop sums RAW h rows only.
__global__ void k_agg(const float* __restrict__ h, const double* __restrict__ mu,
                      const double* __restrict__ rstd, const float* __restrict__ gamma,
                      const float* __restrict__ beta, const unsigned long long* __restrict__ B,
                      const float* __restrict__ w, const float* __restrict__ bp,
                      double* __restrict__ Z1, double* __restrict__ Z3) {
    int i = blockIdx.x;
    int t = threadIdx.x;   // 256
    __shared__ int cols[128];
    __shared__ int s_cnt;
    __shared__ double red[DD];
    __shared__ double red2[DD];
    if (t < 64) {
        unsigned long long word = B[(size_t)i * NW + t];
        int pc = __popcll(word);
        int off = pc;
        for (int dlt = 1; dlt < 64; dlt <<= 1) {
            int n = __shfl_up(off, dlt);
            if (t >= dlt) off += n;
        }
        if (t == 63) s_cnt = off;
        int base = off - pc;
        while (word) {
            int b = (int)__ffsll(word) - 1;
            word &= word - 1;
            if (base < 128) cols[base] = t * 64 + b;
            ++base;
        }
    }
    __syncthreads();
    int cnt = s_cnt;
    double a0=0,a1=0,a2=0,a3=0;
    int j = 0;
    for (; j + 4 <= cnt; j += 4) {
        a0 += (double)h[(size_t)cols[j]   * DD + t];
        a1 += (double)h[(size_t)cols[j+1] * DD + t];
        a2 += (double)h[(size_t)cols[j+2] * DD + t];
        a3 += (double)h[(size_t)cols[j+3] * DD + t];
    }
    for (; j < cnt; ++j) a0 += (double)h[(size_t)cols[j] * DD + t];
    double S = (a0+a1)+(a2+a3);
    double mud = mu[t], rsd = rstd[t];
    double aggd = (S / (double)cnt - mud) * rsd * (double)gamma[t] + (double)beta[t];
    double hni  = ((double)h[(size_t)i * DD + t] - mud) * rsd * (double)gamma[t] + (double)beta[t];
    red[t]  = fabs(hni - aggd);
    red2[t] = aggd * (double)w[t];
    __syncthreads();
    for (int s = 128; s > 0; s >>= 1) {
        if (t < s) { red[t] += red[t + s]; red2[t] += red2[t + s]; }
        __syncthreads();
    }
    if (t == 0) { Z1[i] = red[0]; Z3[i] = red2[0] + (double)bp[0]; }
}

// ---------------- fused scores (fp64 softmax/sigmoids) + top-k bitonic sort ----------------
__global__ void k_scores_topk(const double* __restrict__ Z1, const double* __restrict__ Z3,
                              const double* __restrict__ zpf, const int* __restrict__ degi,
                              const float* __restrict__ sigma1, float* __restrict__ scores,
                              int* __restrict__ idx_int, unsigned long long* __restrict__ S,
                              float* __restrict__ out_idx) {
    __shared__ double red[1024];
    __shared__ unsigned long long keys[NN];
    __shared__ unsigned long long Sl[NW];
    int tid = threadIdx.x;   // 1024
    // --- softmax max ---
    double mx = -1e300;
    for (int i = tid; i < NN; i += 1024) mx = fmax(mx, Z3[i]);
    red[tid] = mx;
    __syncthreads();
    for (int s = 512; s > 0; s >>= 1) {
        if (tid < s) red[tid] = fmax(red[tid], red[tid + s]);
        __syncthreads();
    }
    double m = red[0];
    __syncthreads();
    // --- softmax denom ---
    double se = 0.0;
    for (int i = tid; i < NN; i += 1024) se += exp(Z3[i] - m);
    red[tid] = se;
    __syncthreads();
    for (int s = 512; s > 0; s >>= 1) {
        if (tid < s) red[tid] += red[tid + s];
        __syncthreads();
    }
    double sum = red[0];
    double s1 = (double)sigma1[0];
    // --- scores + sort keys ---
    for (int i = tid; i < NN; i += 1024) {
        double pg = exp(Z3[i] - m) / sum;
        double pl = 1.0 / (1.0 + exp(-(Z1[i] + (double)degi[i])));
        double pt = 1.0 / (1.0 + exp(-(pl + pg)));
        double pf = 1.0 / (1.0 + exp(-zpf[i]));
        float sc = (float)(s1 * pt + (1.0 - s1) * pf);
        scores[i] = sc;
        unsigned int b = __float_as_uint(sc);
        unsigned int ka = (b & 0x80000000u) ? ~b : (b ^ 0x80000000u);  // ascending key
        keys[i] = ((unsigned long long)(~ka) << 32) | (unsigned int)i; // desc score, asc idx
    }
    __syncthreads();
    // --- bitonic sort (4096) ---
    for (int kk = 2; kk <= NN; kk <<= 1) {
        for (int j = kk >> 1; j > 0; j >>= 1) {
            for (int i = tid; i < NN; i += 1024) {
                int ix = i ^ j;
                if (ix > i) {
                    bool up = ((i & kk) == 0);
                    unsigned long long a = keys[i], c = keys[ix];
                    if ((a > c) == up) { keys[i] = c; keys[ix] = a; }
                }
            }
            __syncthreads();
        }
    }
    if (tid < NW) Sl[tid] = 0ull;
    __syncthreads();
    for (int r = tid; r < KK; r += 1024) {
        unsigned int ii = (unsigned int)(keys[r] & 0xffffffffu);
        idx_int[r] = (int)ii;
        out_idx[r] = (float)ii;
        atomicOr(&Sl[ii >> 6], 1ull << (ii & 63));
    }
    __syncthreads();
    if (tid < NW) S[tid] = Sl[tid];
}

// ---------------- h_att = scores[row] * hn ----------------
__global__ void k_hatt(const float* __restrict__ scores, const float* __restrict__ hn,
                       float* __restrict__ ha) {
    int i = blockIdx.x * 256 + threadIdx.x;
    ha[i] = scores[i >> 8] * hn[i];
}

// ---------------- row sums for g_new normalization (broadcast divides col c by rowsum of row c) --
__global__ void k_rowsum(const unsigned long long* __restrict__ T, const int* __restrict__ idx_int,
                         const unsigned long long* __restrict__ S, float* __restrict__ inv_rs) {
    int j = blockIdx.x * 256 + threadIdx.x;   // grid 8
    if (j >= KK) return;
    int r = idx_int[j];
    int c = 0;
    for (int w = 0; w < NW; ++w) c += __popcll(T[(size_t)r * NW + w] & S[w]);
    inv_rs[j] = 1.0f / (float)c;
}

// ---------------- g_new output ----------------
__global__ void k_gnew(const unsigned long long* __restrict__ T, const int* __restrict__ idx_int,
                       const float* __restrict__ inv_rs, float* __restrict__ out) {
    int r = blockIdx.x;
    int tid = threadIdx.x;   // 256
    __shared__ unsigned long long Tl[NW];
    if (tid < NW) Tl[tid] = T[(size_t)idx_int[r] * NW + tid];
    __syncthreads();
    for (int c = tid; c < KK; c += 256) {
        int jc = idx_int[c];
        int bit = (int)((Tl[jc >> 6] >> (jc & 63)) & 1ull);
        out[(size_t)r * KK + c] = bit ? inv_rs[c] : 0.0f;
    }
}

// ---------------- new_h: LDS index list + 4 accumulators over pre-scaled ha rows ----------------
__global__ void k_newh(const unsigned long long* __restrict__ T, const int* __restrict__ idx_int,
                       const float* __restrict__ ha, float* __restrict__ out) {
    int r = blockIdx.x;
    int t = threadIdx.x;   // 256
    __shared__ int cols[2048];
    __shared__ int s_cnt;
    if (t < 64) {
        unsigned long long word = T[(size_t)idx_int[r] * NW + t];
        int pc = __popcll(word);
        int off = pc;
        for (int dlt = 1; dlt < 64; dlt <<= 1) {
            int n = __shfl_up(off, dlt);
            if (t >= dlt) off += n;
        }
        if (t == 63) s_cnt = off;
        int base = off - pc;
        while (word) {
            int b = (int)__ffsll(word) - 1;
            word &= word - 1;
            if (base < 2048) cols[base] = t * 64 + b;
            ++base;
        }
    }
    __syncthreads();
    int cnt = s_cnt < 2048 ? s_cnt : 2048;
    float a0=0.f, a1=0.f, a2=0.f, a3=0.f;
    int j = 0;
    for (; j + 4 <= cnt; j += 4) {
        int c0 = cols[j], c1 = cols[j+1], c2 = cols[j+2], c3 = cols[j+3];
        a0 += ha[(size_t)c0 * DD + t];
        a1 += ha[(size_t)c1 * DD + t];
        a2 += ha[(size_t)c2 * DD + t];
        a3 += ha[(size_t)c3 * DD + t];
    }
    for (; j < cnt; ++j) a0 += ha[(size_t)cols[j] * DD + t];
    out[(size_t)r * DD + t] = (a0 + a1) + (a2 + a3);
}

extern "C" void kernel_launch(void* const* d_in, const int* in_sizes, int n_in,
                              void* d_out, int out_size, void* d_ws, size_t ws_size,
                              hipStream_t stream) {
    const float* g      = (const float*)d_in[0];
    const float* h      = (const float*)d_in[1];
    const float* gamma  = (const float*)d_in[2];
    const float* beta   = (const float*)d_in[3];
    const float* w_proj = (const float*)d_in[4];
    const float* b_proj = (const float*)d_in[5];
    const float* sigma1 = (const float*)d_in[6];

    char* p = (char*)d_ws;
    auto alloc = [&](size_t bytes) -> void* {
        void* q = (void*)p;
        p += (bytes + 255) & ~(size_t)255;
        return q;
    };
    double* mu      = (double*)alloc(DD * 8);
    double* rstd    = (double*)alloc(DD * 8);
    double* psum    = (double*)alloc(256 * DD * 8);
    double* psq     = (double*)alloc(256 * DD * 8);
    double* zpf     = (double*)alloc(NN * 8);
    double* Z1      = (double*)alloc(NN * 8);
    double* Z3      = (double*)alloc(NN * 8);
    int*    degi    = (int*)alloc(NN * 4);
    float*  scores  = (float*)alloc(NN * 4);
    int*    idx_int = (int*)alloc(KK * 4);
    unsigned long long* S = (unsigned long long*)alloc(NW * 8);
    float*  inv_rs  = (float*)alloc(KK * 4);
    unsigned long long* B = (unsigned long long*)alloc((size_t)NN * NW * 8);
    unsigned long long* T = (unsigned long long*)alloc((size_t)NN * NW * 8);
    float*  hn      = (float*)alloc((size_t)NN * DD * 4);
    float*  ha      = (float*)alloc((size_t)NN * DD * 4);

    float* out_gnew = (float*)d_out;                       // KK*KK
    float* out_newh = out_gnew + (size_t)KK * KK;          // KK*DD
    float* out_idx  = out_newh + (size_t)KK * DD;          // KK

    hipLaunchKernelGGL(k_stats_part,  dim3(256), dim3(256),  0, stream, h, psum, psq);
    hipLaunchKernelGGL(k_stats_final, dim3(1),   dim3(1024), 0, stream, psum, psq, mu, rstd);
    hipLaunchKernelGGL(k_norm_zpf,    dim3(NN),  dim3(256),  0, stream, h, mu, rstd, gamma, beta, w_proj, b_proj, hn, zpf);
    hipLaunchKernelGGL(k_bitmask,     dim3(NN),  dim3(256),  0, stream, g, B, degi);
    hipLaunchKernelGGL(k_twohop,      dim3(NN),  dim3(256),  0, stream, B, T);
    hipLaunchKernelGGL(k_agg,         dim3(NN),  dim3(256),  0, stream, h, mu, rstd, gamma, beta, B, w_proj, b_proj, Z1, Z3);
    hipLaunchKernelGGL(k_scores_topk, dim3(1),   dim3(1024), 0, stream, Z1, Z3, zpf, degi, sigma1, scores, idx_int, S, out_idx);
    hipLaunchKernelGGL(k_hatt,        dim3(NN),  dim3(256),  0, stream, scores, hn, ha);
    hipLaunchKernelGGL(k_rowsum,      dim3(8),   dim3(256),  0, stream, T, idx_int, S, inv_rs);
    hipLaunchKernelGGL(k_gnew,        dim3(KK),  dim3(256),  0, stream, T, idx_int, inv_rs, out_gnew);
    hipLaunchKernelGGL(k_newh,        dim3(KK),  dim3(256),  0, stream, T, idx_int, ha, out_newh);
}

// Round 3
// 233.070 us; speedup vs baseline: 1.4978x; 1.2353x over previous
//
#include <hip/hip_runtime.h>
#include <math.h>

#define NN 4096
#define DD 256
#define KK 2048
#define NW 64   // u64 words per bitmask row

// ---------------- fused column stats: partial sum + sumsq (fp64) ----------------
__global__ void k_stats_part(const float* __restrict__ h, double* __restrict__ psum,
                             double* __restrict__ psq) {
    int d = threadIdx.x;
    int b = blockIdx.x;
    int r0 = b * 16;
    double s0=0,s1=0,s2=0,s3=0,q0=0,q1=0,q2=0,q3=0;
    for (int k = 0; k < 16; k += 4) {
        double x0 = (double)h[(size_t)(r0+k+0) * DD + d];
        double x1 = (double)h[(size_t)(r0+k+1) * DD + d];
        double x2 = (double)h[(size_t)(r0+k+2) * DD + d];
        double x3 = (double)h[(size_t)(r0+k+3) * DD + d];
        s0 += x0; q0 += x0*x0;
        s1 += x1; q1 += x1*x1;
        s2 += x2; q2 += x2*x2;
        s3 += x3; q3 += x3*x3;
    }
    psum[b * DD + d] = (s0+s1)+(s2+s3);
    psq [b * DD + d] = (q0+q1)+(q2+q3);
}

__global__ void k_stats_final(const double* __restrict__ psum, const double* __restrict__ psq,
                              double* __restrict__ mu, double* __restrict__ rstd) {
    __shared__ double rs[4][DD];
    __shared__ double rq[4][DD];
    int t = threadIdx.x;
    int d = t & (DD - 1);
    int q = t >> 8;
    double s0=0,s1=0,q0=0,q1=0;
    int b0 = q * 64;
    for (int k = 0; k < 64; k += 2) {
        s0 += psum[(b0+k)   * DD + d];
        s1 += psum[(b0+k+1) * DD + d];
        q0 += psq [(b0+k)   * DD + d];
        q1 += psq [(b0+k+1) * DD + d];
    }
    rs[q][d] = s0 + s1;
    rq[q][d] = q0 + q1;
    __syncthreads();
    if (q == 0) {
        double S  = (rs[0][d]+rs[1][d]) + (rs[2][d]+rs[3][d]);
        double Q  = (rq[0][d]+rq[1][d]) + (rq[2][d]+rq[3][d]);
        double m  = S / (double)NN;
        double var = Q / (double)NN - m * m;
        mu[d]   = m;
        rstd[d] = 1.0 / sqrt(var + 1e-5);
    }
}

// ---------------- normalized h (fp32) + fused zpf = hn . w + b (fp64) ----------------
__global__ void k_norm_zpf(const float* __restrict__ h, const double* __restrict__ mu,
                           const double* __restrict__ rstd, const float* __restrict__ gamma,
                           const float* __restrict__ beta, const float* __restrict__ w,
                           const float* __restrict__ bp, float* __restrict__ hn,
                           double* __restrict__ zpf) {
    __shared__ double red[DD];
    int r = blockIdx.x;
    int d = threadIdx.x;
    size_t i = (size_t)r * DD + d;
    double hnd = ((double)h[i] - mu[d]) * rstd[d] * (double)gamma[d] + (double)beta[d];
    hn[i] = (float)hnd;
    red[d] = hnd * (double)w[d];
    __syncthreads();
    for (int s = 128; s > 0; s >>= 1) {
        if (d < s) red[d] += red[d + s];
        __syncthreads();
    }
    if (d == 0) zpf[r] = red[0] + (double)bp[0];
}

// ---------------- bitmask of g rows + degree ----------------
__global__ void k_bitmask(const float* __restrict__ g, unsigned long long* __restrict__ B,
                          int* __restrict__ degi) {
    int i = blockIdx.x;
    int tid = threadIdx.x;             // 256 = 4 waves
    int w = tid >> 6, l = tid & 63;
    __shared__ int pc[4];
    int local = 0;
    for (int wi = 0; wi < 16; ++wi) {
        int word = wi * 4 + w;
        float v = g[(size_t)i * NN + (size_t)word * 64 + l];
        unsigned long long m = __ballot(v != 0.0f);
        if (l == 0) {
            B[(size_t)i * NW + word] = m;
            local += __popcll(m);
        }
    }
    if (l == 0) pc[w] = local;
    __syncthreads();
    if (tid == 0) degi[i] = pc[0] + pc[1] + pc[2] + pc[3];
}

// ---------------- two-hop bitmask: T[i] = OR_{j in N(i)} B[j], 4-wave split ----------------
__global__ void k_twohop(const unsigned long long* __restrict__ B,
                         unsigned long long* __restrict__ T) {
    int i = blockIdx.x;
    int t = threadIdx.x;       // 256
    int w = t >> 6, l = t & 63;
    __shared__ unsigned long long red[4][NW];
    unsigned long long acc = 0ull;
    for (int wd = w * 16; wd < w * 16 + 16; ++wd) {
        unsigned long long word = B[(size_t)i * NW + wd];
        while (word) {
            int b = (int)__ffsll(word) - 1;
            word &= word - 1;
            acc |= B[(size_t)(wd * 64 + b) * NW + l];
        }
    }
    red[w][l] = acc;
    __syncthreads();
    if (t < NW)
        T[(size_t)i * NW + t] = (red[0][t] | red[1][t]) | (red[2][t] | red[3][t]);
}

// ---------------- agg (sparse avg), Z1, Z3 in fp64 — list-based, 4 accumulators ----------------
__global__ void k_agg(const float* __restrict__ h, const double* __restrict__ mu,
                      const double* __restrict__ rstd, const float* __restrict__ gamma,
                      const float* __restrict__ beta, const unsigned long long* __restrict__ B,
                      const float* __restrict__ w, const float* __restrict__ bp,
                      double* __restrict__ Z1, double* __restrict__ Z3) {
    int i = blockIdx.x;
    int t = threadIdx.x;   // 256
    __shared__ int cols[128];
    __shared__ int s_cnt;
    __shared__ double red[DD];
    __shared__ double red2[DD];
    if (t < 64) {
        unsigned long long word = B[(size_t)i * NW + t];
        int pc = __popcll(word);
        int off = pc;
        for (int dlt = 1; dlt < 64; dlt <<= 1) {
            int n = __shfl_up(off, dlt);
            if (t >= dlt) off += n;
        }
        if (t == 63) s_cnt = off;
        int base = off - pc;
        while (word) {
            int b = (int)__ffsll(word) - 1;
            word &= word - 1;
            if (base < 128) cols[base] = t * 64 + b;
            ++base;
        }
    }
    __syncthreads();
    int cnt = s_cnt;
    double a0=0,a1=0,a2=0,a3=0;
    int j = 0;
    for (; j + 4 <= cnt; j += 4) {
        a0 += (double)h[(size_t)cols[j]   * DD + t];
        a1 += (double)h[(size_t)cols[j+1] * DD + t];
        a2 += (double)h[(size_t)cols[j+2] * DD + t];
        a3 += (double)h[(size_t)cols[j+3] * DD + t];
    }
    for (; j < cnt; ++j) a0 += (double)h[(size_t)cols[j] * DD + t];
    double S = (a0+a1)+(a2+a3);
    double mud = mu[t], rsd = rstd[t];
    double aggd = (S / (double)cnt - mud) * rsd * (double)gamma[t] + (double)beta[t];
    double hni  = ((double)h[(size_t)i * DD + t] - mud) * rsd * (double)gamma[t] + (double)beta[t];
    red[t]  = fabs(hni - aggd);
    red2[t] = aggd * (double)w[t];
    __syncthreads();
    for (int s = 128; s > 0; s >>= 1) {
        if (t < s) { red[t] += red[t + s]; red2[t] += red2[t + s]; }
        __syncthreads();
    }
    if (t == 0) { Z1[i] = red[0]; Z3[i] = red2[0] + (double)bp[0]; }
}

// ---------------- softmax reduction stage 1: 32 blocks x 128, partial max + sumexp ----------------
__global__ void k_red1(const double* __restrict__ Z3, double* __restrict__ pm,
                       double* __restrict__ ps) {
    __shared__ double sm[128];
    __shared__ double ss[128];
    int t = threadIdx.x;
    int b = blockIdx.x;
    double z = Z3[b * 128 + t];
    sm[t] = z;
    __syncthreads();
    for (int s = 64; s > 0; s >>= 1) {
        if (t < s) sm[t] = fmax(sm[t], sm[t + s]);
        __syncthreads();
    }
    double m = sm[0];
    ss[t] = exp(z - m);
    __syncthreads();
    for (int s = 64; s > 0; s >>= 1) {
        if (t < s) ss[t] += ss[t + s];
        __syncthreads();
    }
    if (t == 0) { pm[b] = m; ps[b] = ss[0]; }
}

// ---------------- stage 2: one wave combines 32 partials; also zeroes S ----------------
__global__ void k_red2(const double* __restrict__ pm, const double* __restrict__ ps,
                       double* __restrict__ gms, unsigned long long* __restrict__ S) {
    int t = threadIdx.x;   // 64
    double m = (t < 32) ? pm[t] : -1e300;
    double s = (t < 32) ? ps[t] : 0.0;
    double M = m;
    for (int off = 32; off > 0; off >>= 1) M = fmax(M, __shfl_down(M, off));
    M = __shfl(M, 0);
    double sc = s * exp(m - M);
    for (int off = 32; off > 0; off >>= 1) sc += __shfl_down(sc, off);
    if (t == 0) { gms[0] = M; gms[1] = sc; }
    S[t] = 0ull;
}

// ---------------- scores (fp64) + u64 sort keys (desc score, asc idx) ----------------
__global__ void k_scorekeys(const double* __restrict__ Z1, const double* __restrict__ Z3,
                            const double* __restrict__ zpf, const int* __restrict__ degi,
                            const float* __restrict__ sigma1, const double* __restrict__ gms,
                            float* __restrict__ scores, unsigned long long* __restrict__ keys) {
    int i = blockIdx.x * 256 + threadIdx.x;
    double M = gms[0], sum = gms[1];
    double s1 = (double)sigma1[0];
    double pg = exp(Z3[i] - M) / sum;
    double pl = 1.0 / (1.0 + exp(-(Z1[i] + (double)degi[i])));
    double pt = 1.0 / (1.0 + exp(-(pl + pg)));
    double pf = 1.0 / (1.0 + exp(-zpf[i]));
    float sc = (float)(s1 * pt + (1.0 - s1) * pf);
    scores[i] = sc;
    unsigned int b = __float_as_uint(sc);
    unsigned int ka = (b & 0x80000000u) ? ~b : (b ^ 0x80000000u);   // ascending order key
    keys[i] = ((unsigned long long)(~ka) << 32) | (unsigned int)i;  // asc sort = desc score, asc idx
}

// ---------------- rank-by-counting top-k scatter ----------------
// grid 256 blocks x 256 threads: block b ranks i in [16b,16b+16), 16 threads per i.
// j interleaved mod 16 -> 16 lanes hit 16 distinct even banks (conflict-free).
__global__ void k_rank(const unsigned long long* __restrict__ keys, int* __restrict__ idx_int,
                       unsigned long long* __restrict__ S, float* __restrict__ out_idx) {
    __shared__ unsigned long long Kl[NN];
    int t = threadIdx.x;
    for (int i = t; i < NN; i += 256) Kl[i] = keys[i];
    __syncthreads();
    int il = t >> 4, sub = t & 15;
    int i = blockIdx.x * 16 + il;
    unsigned long long ki = Kl[i];
    int c0 = 0, c1 = 0, c2 = 0, c3 = 0;
    for (int jj = 0; jj < 256; jj += 4) {
        int j = sub + (jj << 4);
        c0 += (Kl[j]      < ki) ? 1 : 0;
        c1 += (Kl[j + 16] < ki) ? 1 : 0;
        c2 += (Kl[j + 32] < ki) ? 1 : 0;
        c3 += (Kl[j + 48] < ki) ? 1 : 0;
    }
    int cnt = (c0 + c1) + (c2 + c3);
    for (int off = 8; off > 0; off >>= 1) cnt += __shfl_down(cnt, off, 16);
    if (sub == 0) {
        int rank = cnt;   // exact bijection: keys are unique
        if (rank < KK) {
            idx_int[rank] = i;
            out_idx[rank] = (float)i;
            atomicOr(&S[i >> 6], 1ull << (i & 63));
        }
    }
}

// ---------------- h_att = scores[row] * hn ----------------
__global__ void k_hatt(const float* __restrict__ scores, const float* __restrict__ hn,
                       float* __restrict__ ha) {
    int i = blockIdx.x * 256 + threadIdx.x;
    ha[i] = scores[i >> 8] * hn[i];
}

// ---------------- row sums for g_new normalization (broadcast divides col c by rowsum of row c) --
__global__ void k_rowsum(const unsigned long long* __restrict__ T, const int* __restrict__ idx_int,
                         const unsigned long long* __restrict__ S, float* __restrict__ inv_rs) {
    int j = blockIdx.x * 256 + threadIdx.x;   // grid 8
    if (j >= KK) return;
    int r = idx_int[j];
    int c = 0;
    for (int w = 0; w < NW; ++w) c += __popcll(T[(size_t)r * NW + w] & S[w]);
    inv_rs[j] = 1.0f / (float)c;
}

// ---------------- g_new output ----------------
__global__ void k_gnew(const unsigned long long* __restrict__ T, const int* __restrict__ idx_int,
                       const float* __restrict__ inv_rs, float* __restrict__ out) {
    int r = blockIdx.x;
    int tid = threadIdx.x;   // 256
    __shared__ unsigned long long Tl[NW];
    if (tid < NW) Tl[tid] = T[(size_t)idx_int[r] * NW + tid];
    __syncthreads();
    for (int c = tid; c < KK; c += 256) {
        int jc = idx_int[c];
        int bit = (int)((Tl[jc >> 6] >> (jc & 63)) & 1ull);
        out[(size_t)r * KK + c] = bit ? inv_rs[c] : 0.0f;
    }
}

// ---------------- new_h: LDS index list + 8 accumulators over pre-scaled ha rows ----------------
__global__ void k_newh(const unsigned long long* __restrict__ T, const int* __restrict__ idx_int,
                       const float* __restrict__ ha, float* __restrict__ out) {
    int r = blockIdx.x;
    int t = threadIdx.x;   // 256
    __shared__ int cols[2048];
    __shared__ int s_cnt;
    if (t < 64) {
        unsigned long long word = T[(size_t)idx_int[r] * NW + t];
        int pc = __popcll(word);
        int off = pc;
        for (int dlt = 1; dlt < 64; dlt <<= 1) {
            int n = __shfl_up(off, dlt);
            if (t >= dlt) off += n;
        }
        if (t == 63) s_cnt = off;
        int base = off - pc;
        while (word) {
            int b = (int)__ffsll(word) - 1;
            word &= word - 1;
            if (base < 2048) cols[base] = t * 64 + b;
            ++base;
        }
    }
    __syncthreads();
    int cnt = s_cnt < 2048 ? s_cnt : 2048;
    float a0=0.f,a1=0.f,a2=0.f,a3=0.f,a4=0.f,a5=0.f,a6=0.f,a7=0.f;
    int j = 0;
    for (; j + 8 <= cnt; j += 8) {
        int c0=cols[j],c1=cols[j+1],c2=cols[j+2],c3=cols[j+3];
        int c4=cols[j+4],c5=cols[j+5],c6=cols[j+6],c7=cols[j+7];
        a0 += ha[(size_t)c0 * DD + t];
        a1 += ha[(size_t)c1 * DD + t];
        a2 += ha[(size_t)c2 * DD + t];
        a3 += ha[(size_t)c3 * DD + t];
        a4 += ha[(size_t)c4 * DD + t];
        a5 += ha[(size_t)c5 * DD + t];
        a6 += ha[(size_t)c6 * DD + t];
        a7 += ha[(size_t)c7 * DD + t];
    }
    for (; j < cnt; ++j) a0 += ha[(size_t)cols[j] * DD + t];
    out[(size_t)r * DD + t] = ((a0+a1)+(a2+a3)) + ((a4+a5)+(a6+a7));
}

extern "C" void kernel_launch(void* const* d_in, const int* in_sizes, int n_in,
                              void* d_out, int out_size, void* d_ws, size_t ws_size,
                              hipStream_t stream) {
    const float* g      = (const float*)d_in[0];
    const float* h      = (const float*)d_in[1];
    const float* gamma  = (const float*)d_in[2];
    const float* beta   = (const float*)d_in[3];
    const float* w_proj = (const float*)d_in[4];
    const float* b_proj = (const float*)d_in[5];
    const float* sigma1 = (const float*)d_in[6];

    char* p = (char*)d_ws;
    auto alloc = [&](size_t bytes) -> void* {
        void* q = (void*)p;
        p += (bytes + 255) & ~(size_t)255;
        return q;
    };
    double* mu      = (double*)alloc(DD * 8);
    double* rstd    = (double*)alloc(DD * 8);
    double* psum    = (double*)alloc(256 * DD * 8);
    double* psq     = (double*)alloc(256 * DD * 8);
    double* zpf     = (double*)alloc(NN * 8);
    double* Z1      = (double*)alloc(NN * 8);
    double* Z3      = (double*)alloc(NN * 8);
    double* pm      = (double*)alloc(32 * 8);
    double* ps      = (double*)alloc(32 * 8);
    double* gms     = (double*)alloc(2 * 8);
    int*    degi    = (int*)alloc(NN * 4);
    float*  scores  = (float*)alloc(NN * 4);
    unsigned long long* keys = (unsigned long long*)alloc(NN * 8);
    int*    idx_int = (int*)alloc(KK * 4);
    unsigned long long* S = (unsigned long long*)alloc(NW * 8);
    float*  inv_rs  = (float*)alloc(KK * 4);
    unsigned long long* B = (unsigned long long*)alloc((size_t)NN * NW * 8);
    unsigned long long* T = (unsigned long long*)alloc((size_t)NN * NW * 8);
    float*  hn      = (float*)alloc((size_t)NN * DD * 4);
    float*  ha      = (float*)alloc((size_t)NN * DD * 4);

    float* out_gnew = (float*)d_out;                       // KK*KK
    float* out_newh = out_gnew + (size_t)KK * KK;          // KK*DD
    float* out_idx  = out_newh + (size_t)KK * DD;          // KK

    hipLaunchKernelGGL(k_stats_part,  dim3(256), dim3(256),  0, stream, h, psum, psq);
    hipLaunchKernelGGL(k_stats_final, dim3(1),   dim3(1024), 0, stream, psum, psq, mu, rstd);
    hipLaunchKernelGGL(k_norm_zpf,    dim3(NN),  dim3(256),  0, stream, h, mu, rstd, gamma, beta, w_proj, b_proj, hn, zpf);
    hipLaunchKernelGGL(k_bitmask,     dim3(NN),  dim3(256),  0, stream, g, B, degi);
    hipLaunchKernelGGL(k_twohop,      dim3(NN),  dim3(256),  0, stream, B, T);
    hipLaunchKernelGGL(k_agg,         dim3(NN),  dim3(256),  0, stream, h, mu, rstd, gamma, beta, B, w_proj, b_proj, Z1, Z3);
    hipLaunchKernelGGL(k_red1,        dim3(32),  dim3(128),  0, stream, Z3, pm, ps);
    hipLaunchKernelGGL(k_red2,        dim3(1),   dim3(64),   0, stream, pm, ps, gms, S);
    hipLaunchKernelGGL(k_scorekeys,   dim3(16),  dim3(256),  0, stream, Z1, Z3, zpf, degi, sigma1, gms, scores, keys);
    hipLaunchKernelGGL(k_rank,        dim3(256), dim3(256),  0, stream, keys, idx_int, S, out_idx);
    hipLaunchKernelGGL(k_hatt,        dim3(NN),  dim3(256),  0, stream, scores, hn, ha);
    hipLaunchKernelGGL(k_rowsum,      dim3(8),   dim3(256),  0, stream, T, idx_int, S, inv_rs);
    hipLaunchKernelGGL(k_gnew,        dim3(KK),  dim3(256),  0, stream, T, idx_int, inv_rs, out_gnew);
    hipLaunchKernelGGL(k_newh,        dim3(KK),  dim3(256),  0, stream, T, idx_int, ha, out_newh);
}

// Round 4
// 202.239 us; speedup vs baseline: 1.7262x; 1.1525x over previous
//
#include <hip/hip_runtime.h>
#include <math.h>

#define NN 4096
#define DD 256
#define KK 2048
#define NW 64   // u64 words per bitmask row

// ---------------- fused column stats: partial sum + sumsq (fp64) ----------------
// grid 64, block 256. Block b handles rows [64b, 64b+64).
__global__ void k_stats_part(const float* __restrict__ h, double* __restrict__ psum,
                             double* __restrict__ psq) {
    int d = threadIdx.x;
    int b = blockIdx.x;
    int r0 = b * 64;
    double s0=0,s1=0,s2=0,s3=0,q0=0,q1=0,q2=0,q3=0;
    for (int k = 0; k < 64; k += 4) {
        double x0 = (double)h[(size_t)(r0+k+0) * DD + d];
        double x1 = (double)h[(size_t)(r0+k+1) * DD + d];
        double x2 = (double)h[(size_t)(r0+k+2) * DD + d];
        double x3 = (double)h[(size_t)(r0+k+3) * DD + d];
        s0 += x0; q0 += x0*x0;
        s1 += x1; q1 += x1*x1;
        s2 += x2; q2 += x2*x2;
        s3 += x3; q3 += x3*x3;
    }
    psum[b * DD + d] = (s0+s1)+(s2+s3);
    psq [b * DD + d] = (q0+q1)+(q2+q3);
}

// 1 block, 1024 threads: thread = d + 256*q, q in 0..3 each sums 16 partials.
__global__ void k_stats_final(const double* __restrict__ psum, const double* __restrict__ psq,
                              double* __restrict__ mu, double* __restrict__ rstd) {
    __shared__ double rs[4][DD];
    __shared__ double rq[4][DD];
    int t = threadIdx.x;
    int d = t & (DD - 1);
    int q = t >> 8;
    double s0=0,s1=0,q0=0,q1=0;
    int b0 = q * 16;
    for (int k = 0; k < 16; k += 2) {
        s0 += psum[(b0+k)   * DD + d];
        s1 += psum[(b0+k+1) * DD + d];
        q0 += psq [(b0+k)   * DD + d];
        q1 += psq [(b0+k+1) * DD + d];
    }
    rs[q][d] = s0 + s1;
    rq[q][d] = q0 + q1;
    __syncthreads();
    if (q == 0) {
        double S  = (rs[0][d]+rs[1][d]) + (rs[2][d]+rs[3][d]);
        double Q  = (rq[0][d]+rq[1][d]) + (rq[2][d]+rq[3][d]);
        double m  = S / (double)NN;
        double var = Q / (double)NN - m * m;
        mu[d]   = m;
        rstd[d] = 1.0 / sqrt(var + 1e-5);
    }
}

// ---------------- normalized h (fp32) + fused zpf = hn . w + b (fp64) ----------------
__global__ void k_norm_zpf(const float* __restrict__ h, const double* __restrict__ mu,
                           const double* __restrict__ rstd, const float* __restrict__ gamma,
                           const float* __restrict__ beta, const float* __restrict__ w,
                           const float* __restrict__ bp, float* __restrict__ hn,
                           double* __restrict__ zpf) {
    __shared__ double red[DD];
    int r = blockIdx.x;
    int d = threadIdx.x;
    size_t i = (size_t)r * DD + d;
    double hnd = ((double)h[i] - mu[d]) * rstd[d] * (double)gamma[d] + (double)beta[d];
    hn[i] = (float)hnd;
    red[d] = hnd * (double)w[d];
    __syncthreads();
    for (int s = 128; s > 0; s >>= 1) {
        if (d < s) red[d] += red[d + s];
        __syncthreads();
    }
    if (d == 0) zpf[r] = red[0] + (double)bp[0];
}

// ---------------- bitmask of g rows, dwordx4 loads + 16-lane shfl-xor word assembly ----------------
__global__ void k_bitmask(const float* __restrict__ g, unsigned long long* __restrict__ B) {
    int i = blockIdx.x;
    int t = threadIdx.x;           // 256
    int q = t >> 6, l = t & 63;
    const float4* g4 = (const float4*)(g + (size_t)i * NN);
    for (int wi = 0; wi < 4; ++wi) {
        float4 v = g4[q * 256 + wi * 64 + l];   // cols 1024q + 256wi + 4l ..+3
        unsigned int nib = (unsigned int)(v.x != 0.f)
                         | ((unsigned int)(v.y != 0.f) << 1)
                         | ((unsigned int)(v.z != 0.f) << 2)
                         | ((unsigned int)(v.w != 0.f) << 3);
        unsigned long long word = (unsigned long long)nib << (4 * (l & 15));
        unsigned int lo = (unsigned int)word, hi = (unsigned int)(word >> 32);
        for (int s = 1; s < 16; s <<= 1) {
            lo |= __shfl_xor(lo, s, 16);
            hi |= __shfl_xor(hi, s, 16);
        }
        if ((l & 15) == 0)
            B[(size_t)i * NW + 16 * q + 4 * wi + (l >> 4)] =
                ((unsigned long long)hi << 32) | lo;
    }
}

// ---------------- two-hop bitmask: list-based, 4-wave split, 2-deep unroll ----------------
__global__ void k_twohop(const unsigned long long* __restrict__ B,
                         unsigned long long* __restrict__ T) {
    int i = blockIdx.x;
    int t = threadIdx.x;       // 256
    int w = t >> 6, l = t & 63;
    __shared__ int cols[128];
    __shared__ int s_cnt;
    __shared__ unsigned long long red[4][NW];
    if (t < 64) {
        unsigned long long word = B[(size_t)i * NW + t];
        int pc = __popcll(word);
        int off = pc;
        for (int dlt = 1; dlt < 64; dlt <<= 1) {
            int n = __shfl_up(off, dlt);
            if (t >= dlt) off += n;
        }
        if (t == 63) s_cnt = off;
        int base = off - pc;
        while (word) {
            int b = (int)__ffsll(word) - 1;
            word &= word - 1;
            if (base < 128) cols[base] = t * 64 + b;
            ++base;
        }
    }
    __syncthreads();
    int cnt = s_cnt;
    unsigned long long a0 = 0ull, a1 = 0ull;
    int j = w;
    for (; j + 4 < cnt; j += 8) {
        a0 |= B[(size_t)cols[j]     * NW + l];
        a1 |= B[(size_t)cols[j + 4] * NW + l];
    }
    for (; j < cnt; j += 4) a0 |= B[(size_t)cols[j] * NW + l];
    red[w][l] = a0 | a1;
    __syncthreads();
    if (t < NW)
        T[(size_t)i * NW + t] = (red[0][t] | red[1][t]) | (red[2][t] | red[3][t]);
}

// ---------------- agg (sparse avg), Z1, Z3 fp64 — 4-wave float4 gather; emits degi ----------------
__global__ void k_agg(const float* __restrict__ h, const double* __restrict__ mu,
                      const double* __restrict__ rstd, const float* __restrict__ gamma,
                      const float* __restrict__ beta, const unsigned long long* __restrict__ B,
                      const float* __restrict__ w, const float* __restrict__ bp,
                      double* __restrict__ Z1, double* __restrict__ Z3,
                      int* __restrict__ degi) {
    int i = blockIdx.x;
    int t = threadIdx.x;   // 256
    int wv = t >> 6, l = t & 63;
    __shared__ int cols[128];
    __shared__ int s_cnt;
    __shared__ double redd[4][DD];   // 8 KB partials
    __shared__ double red[DD];
    __shared__ double red2[DD];
    if (t < 64) {
        unsigned long long word = B[(size_t)i * NW + t];
        int pc = __popcll(word);
        int off = pc;
        for (int dlt = 1; dlt < 64; dlt <<= 1) {
            int n = __shfl_up(off, dlt);
            if (t >= dlt) off += n;
        }
        if (t == 63) s_cnt = off;
        int base = off - pc;
        while (word) {
            int b = (int)__ffsll(word) - 1;
            word &= word - 1;
            if (base < 128) cols[base] = t * 64 + b;
            ++base;
        }
    }
    __syncthreads();
    int cnt = s_cnt;
    if (t == 0) degi[i] = cnt;
    const float4* h4 = (const float4*)h;   // row stride 64 float4s
    double a0=0,a1=0,a2=0,a3=0,b0=0,b1=0,b2=0,b3=0;
    int j = wv;
    for (; j + 4 < cnt; j += 8) {
        float4 v0 = h4[(size_t)cols[j]     * 64 + l];
        float4 v1 = h4[(size_t)cols[j + 4] * 64 + l];
        a0 += (double)v0.x; a1 += (double)v0.y; a2 += (double)v0.z; a3 += (double)v0.w;
        b0 += (double)v1.x; b1 += (double)v1.y; b2 += (double)v1.z; b3 += (double)v1.w;
    }
    for (; j < cnt; j += 4) {
        float4 v0 = h4[(size_t)cols[j] * 64 + l];
        a0 += (double)v0.x; a1 += (double)v0.y; a2 += (double)v0.z; a3 += (double)v0.w;
    }
    redd[wv][4*l+0] = a0 + b0;
    redd[wv][4*l+1] = a1 + b1;
    redd[wv][4*l+2] = a2 + b2;
    redd[wv][4*l+3] = a3 + b3;
    __syncthreads();
    double S = (redd[0][t] + redd[1][t]) + (redd[2][t] + redd[3][t]);
    double mud = mu[t], rsd = rstd[t];
    double aggd = (S / (double)cnt - mud) * rsd * (double)gamma[t] + (double)beta[t];
    double hni  = ((double)h[(size_t)i * DD + t] - mud) * rsd * (double)gamma[t] + (double)beta[t];
    red[t]  = fabs(hni - aggd);
    red2[t] = aggd * (double)w[t];
    __syncthreads();
    for (int s = 128; s > 0; s >>= 1) {
        if (t < s) { red[t] += red[t + s]; red2[t] += red2[t + s]; }
        __syncthreads();
    }
    if (t == 0) { Z1[i] = red[0]; Z3[i] = red2[0] + (double)bp[0]; }
}

// ---------------- softmax reduction stage 1: 32 blocks x 128; block 0 zeroes S ----------------
__global__ void k_red1(const double* __restrict__ Z3, double* __restrict__ pm,
                       double* __restrict__ ps, unsigned long long* __restrict__ S) {
    __shared__ double sm[128];
    __shared__ double ss[128];
    int t = threadIdx.x;
    int b = blockIdx.x;
    if (b == 0 && t < NW) S[t] = 0ull;
    double z = Z3[b * 128 + t];
    sm[t] = z;
    __syncthreads();
    for (int s = 64; s > 0; s >>= 1) {
        if (t < s) sm[t] = fmax(sm[t], sm[t + s]);
        __syncthreads();
    }
    double m = sm[0];
    ss[t] = exp(z - m);
    __syncthreads();
    for (int s = 64; s > 0; s >>= 1) {
        if (t < s) ss[t] += ss[t + s];
        __syncthreads();
    }
    if (t == 0) { pm[b] = m; ps[b] = ss[0]; }
}

// ---------------- scores (fp64) + u64 sort keys; each block combines the 32 partials ----------------
__global__ void k_scorekeys(const double* __restrict__ Z1, const double* __restrict__ Z3,
                            const double* __restrict__ zpf, const int* __restrict__ degi,
                            const float* __restrict__ sigma1, const double* __restrict__ pm,
                            const double* __restrict__ ps, float* __restrict__ scores,
                            unsigned long long* __restrict__ keys) {
    int i = blockIdx.x * 256 + threadIdx.x;
    double M = -1e300;
    for (int b = 0; b < 32; ++b) M = fmax(M, pm[b]);
    double sum = 0.0;
    for (int b = 0; b < 32; ++b) sum += ps[b] * exp(pm[b] - M);
    double s1 = (double)sigma1[0];
    double pg = exp(Z3[i] - M) / sum;
    double pl = 1.0 / (1.0 + exp(-(Z1[i] + (double)degi[i])));
    double pt = 1.0 / (1.0 + exp(-(pl + pg)));
    double pf = 1.0 / (1.0 + exp(-zpf[i]));
    float sc = (float)(s1 * pt + (1.0 - s1) * pf);
    scores[i] = sc;
    unsigned int b2 = __float_as_uint(sc);
    unsigned int ka = (b2 & 0x80000000u) ? ~b2 : (b2 ^ 0x80000000u);  // ascending order key
    keys[i] = ((unsigned long long)(~ka) << 32) | (unsigned int)i;    // asc = desc score, asc idx
}

// ---------------- rank-by-counting top-k scatter ----------------
__global__ void k_rank(const unsigned long long* __restrict__ keys, int* __restrict__ idx_int,
                       unsigned long long* __restrict__ S, float* __restrict__ out_idx) {
    __shared__ unsigned long long Kl[NN];
    int t = threadIdx.x;
    for (int i = t; i < NN; i += 256) Kl[i] = keys[i];
    __syncthreads();
    int il = t >> 4, sub = t & 15;
    int i = blockIdx.x * 16 + il;
    unsigned long long ki = Kl[i];
    int c0 = 0, c1 = 0, c2 = 0, c3 = 0;
    for (int jj = 0; jj < 256; jj += 4) {
        int j = sub + (jj << 4);
        c0 += (Kl[j]      < ki) ? 1 : 0;
        c1 += (Kl[j + 16] < ki) ? 1 : 0;
        c2 += (Kl[j + 32] < ki) ? 1 : 0;
        c3 += (Kl[j + 48] < ki) ? 1 : 0;
    }
    int cnt = (c0 + c1) + (c2 + c3);
    for (int off = 8; off > 0; off >>= 1) cnt += __shfl_down(cnt, off, 16);
    if (sub == 0) {
        int rank = cnt;   // exact bijection: keys are unique
        if (rank < KK) {
            idx_int[rank] = i;
            out_idx[rank] = (float)i;
            atomicOr(&S[i >> 6], 1ull << (i & 63));
        }
    }
}

// ---------------- row sums for g_new normalization (broadcast divides col c by rowsum of row c) --
__global__ void k_rowsum(const unsigned long long* __restrict__ T, const int* __restrict__ idx_int,
                         const unsigned long long* __restrict__ S, float* __restrict__ inv_rs) {
    int j = blockIdx.x * 256 + threadIdx.x;   // grid 8
    if (j >= KK) return;
    int r = idx_int[j];
    int c = 0;
    for (int w = 0; w < NW; ++w) c += __popcll(T[(size_t)r * NW + w] & S[w]);
    inv_rs[j] = 1.0f / (float)c;
}

// ---------------- g_new output: int4 idx gather + float4 stores ----------------
__global__ void k_gnew(const unsigned long long* __restrict__ T, const int* __restrict__ idx_int,
                       const float* __restrict__ inv_rs, float* __restrict__ out) {
    int r = blockIdx.x;
    int t = threadIdx.x;   // 256
    __shared__ unsigned long long Tl[NW];
    if (t < NW) Tl[t] = T[(size_t)idx_int[r] * NW + t];
    __syncthreads();
    const int4*   idx4 = (const int4*)idx_int;
    const float4* irs4 = (const float4*)inv_rs;
    float4* out4 = (float4*)(out + (size_t)r * KK);
    for (int c4 = t; c4 < KK / 4; c4 += 256) {
        int4 jc = idx4[c4];
        float4 iv = irs4[c4];
        float4 o;
        o.x = ((Tl[jc.x >> 6] >> (jc.x & 63)) & 1ull) ? iv.x : 0.0f;
        o.y = ((Tl[jc.y >> 6] >> (jc.y & 63)) & 1ull) ? iv.y : 0.0f;
        o.z = ((Tl[jc.z >> 6] >> (jc.z & 63)) & 1ull) ? iv.z : 0.0f;
        o.w = ((Tl[jc.w >> 6] >> (jc.w & 63)) & 1ull) ? iv.w : 0.0f;
        out4[c4] = o;
    }
}

// ---------------- new_h: 4-wave float4 gather of hn with fused score scaling ----------------
__global__ void k_newh(const unsigned long long* __restrict__ T, const int* __restrict__ idx_int,
                       const float* __restrict__ scores, const float* __restrict__ hn,
                       float* __restrict__ out) {
    int r = blockIdx.x;
    int t = threadIdx.x;   // 256
    int wv = t >> 6, l = t & 63;
    __shared__ int cols[2048];
    __shared__ int s_cnt;
    __shared__ float4 red[4][64];
    if (t < 64) {
        unsigned long long word = T[(size_t)idx_int[r] * NW + t];
        int pc = __popcll(word);
        int off = pc;
        for (int dlt = 1; dlt < 64; dlt <<= 1) {
            int n = __shfl_up(off, dlt);
            if (t >= dlt) off += n;
        }
        if (t == 63) s_cnt = off;
        int base = off - pc;
        while (word) {
            int b = (int)__ffsll(word) - 1;
            word &= word - 1;
            if (base < 2048) cols[base] = t * 64 + b;
            ++base;
        }
    }
    __syncthreads();
    int cnt = s_cnt < 2048 ? s_cnt : 2048;
    const float4* hn4 = (const float4*)hn;   // row stride 64 float4s
    float4 a0 = {0,0,0,0}, a1 = {0,0,0,0};
    int j = wv;
    for (; j + 4 < cnt; j += 8) {
        int c0 = cols[j], c1 = cols[j + 4];
        float s0 = scores[c0], s1 = scores[c1];
        float4 v0 = hn4[(size_t)c0 * 64 + l];
        float4 v1 = hn4[(size_t)c1 * 64 + l];
        a0.x = fmaf(s0, v0.x, a0.x); a0.y = fmaf(s0, v0.y, a0.y);
        a0.z = fmaf(s0, v0.z, a0.z); a0.w = fmaf(s0, v0.w, a0.w);
        a1.x = fmaf(s1, v1.x, a1.x); a1.y = fmaf(s1, v1.y, a1.y);
        a1.z = fmaf(s1, v1.z, a1.z); a1.w = fmaf(s1, v1.w, a1.w);
    }
    for (; j < cnt; j += 4) {
        int c0 = cols[j];
        float s0 = scores[c0];
        float4 v0 = hn4[(size_t)c0 * 64 + l];
        a0.x = fmaf(s0, v0.x, a0.x); a0.y = fmaf(s0, v0.y, a0.y);
        a0.z = fmaf(s0, v0.z, a0.z); a0.w = fmaf(s0, v0.w, a0.w);
    }
    float4 acc;
    acc.x = a0.x + a1.x; acc.y = a0.y + a1.y; acc.z = a0.z + a1.z; acc.w = a0.w + a1.w;
    red[wv][l] = acc;
    __syncthreads();
    if (t < 64) {
        float4 r0 = red[0][t], r1 = red[1][t], r2 = red[2][t], r3 = red[3][t];
        float4 o;
        o.x = (r0.x + r1.x) + (r2.x + r3.x);
        o.y = (r0.y + r1.y) + (r2.y + r3.y);
        o.z = (r0.z + r1.z) + (r2.z + r3.z);
        o.w = (r0.w + r1.w) + (r2.w + r3.w);
        ((float4*)(out + (size_t)r * DD))[t] = o;
    }
}

extern "C" void kernel_launch(void* const* d_in, const int* in_sizes, int n_in,
                              void* d_out, int out_size, void* d_ws, size_t ws_size,
                              hipStream_t stream) {
    const float* g      = (const float*)d_in[0];
    const float* h      = (const float*)d_in[1];
    const float* gamma  = (const float*)d_in[2];
    const float* beta   = (const float*)d_in[3];
    const float* w_proj = (const float*)d_in[4];
    const float* b_proj = (const float*)d_in[5];
    const float* sigma1 = (const float*)d_in[6];

    char* p = (char*)d_ws;
    auto alloc = [&](size_t bytes) -> void* {
        void* q = (void*)p;
        p += (bytes + 255) & ~(size_t)255;
        return q;
    };
    double* mu      = (double*)alloc(DD * 8);
    double* rstd    = (double*)alloc(DD * 8);
    double* psum    = (double*)alloc(64 * DD * 8);
    double* psq     = (double*)alloc(64 * DD * 8);
    double* zpf     = (double*)alloc(NN * 8);
    double* Z1      = (double*)alloc(NN * 8);
    double* Z3      = (double*)alloc(NN * 8);
    double* pm      = (double*)alloc(32 * 8);
    double* ps      = (double*)alloc(32 * 8);
    int*    degi    = (int*)alloc(NN * 4);
    float*  scores  = (float*)alloc(NN * 4);
    unsigned long long* keys = (unsigned long long*)alloc(NN * 8);
    int*    idx_int = (int*)alloc(KK * 4);
    unsigned long long* S = (unsigned long long*)alloc(NW * 8);
    float*  inv_rs  = (float*)alloc(KK * 4);
    unsigned long long* B = (unsigned long long*)alloc((size_t)NN * NW * 8);
    unsigned long long* T = (unsigned long long*)alloc((size_t)NN * NW * 8);
    float*  hn      = (float*)alloc((size_t)NN * DD * 4);

    float* out_gnew = (float*)d_out;                       // KK*KK
    float* out_newh = out_gnew + (size_t)KK * KK;          // KK*DD
    float* out_idx  = out_newh + (size_t)KK * DD;          // KK

    hipLaunchKernelGGL(k_stats_part,  dim3(64),  dim3(256),  0, stream, h, psum, psq);
    hipLaunchKernelGGL(k_stats_final, dim3(1),   dim3(1024), 0, stream, psum, psq, mu, rstd);
    hipLaunchKernelGGL(k_norm_zpf,    dim3(NN),  dim3(256),  0, stream, h, mu, rstd, gamma, beta, w_proj, b_proj, hn, zpf);
    hipLaunchKernelGGL(k_bitmask,     dim3(NN),  dim3(256),  0, stream, g, B);
    hipLaunchKernelGGL(k_twohop,      dim3(NN),  dim3(256),  0, stream, B, T);
    hipLaunchKernelGGL(k_agg,         dim3(NN),  dim3(256),  0, stream, h, mu, rstd, gamma, beta, B, w_proj, b_proj, Z1, Z3, degi);
    hipLaunchKernelGGL(k_red1,        dim3(32),  dim3(128),  0, stream, Z3, pm, ps, S);
    hipLaunchKernelGGL(k_scorekeys,   dim3(16),  dim3(256),  0, stream, Z1, Z3, zpf, degi, sigma1, pm, ps, scores, keys);
    hipLaunchKernelGGL(k_rank,        dim3(256), dim3(256),  0, stream, keys, idx_int, S, out_idx);
    hipLaunchKernelGGL(k_rowsum,      dim3(8),   dim3(256),  0, stream, T, idx_int, S, inv_rs);
    hipLaunchKernelGGL(k_gnew,        dim3(KK),  dim3(256),  0, stream, T, idx_int, inv_rs, out_gnew);
    hipLaunchKernelGGL(k_newh,        dim3(KK),  dim3(256),  0, stream, T, idx_int, scores, hn, out_newh);
}

// Round 5
// 185.429 us; speedup vs baseline: 1.8827x; 1.0907x over previous
//
#include <hip/hip_runtime.h>
#include <math.h>

#define NN 4096
#define DD 256
#define KK 2048
#define NW 64   // u64 words per bitmask row

// Build sorted column list for bitmask row r into LDS `cols` (one wave, lane l).
// Returns total bit count. List is ascending.
__device__ __forceinline__ int build_list(const unsigned long long* __restrict__ B, int r,
                                          int l, int* cols, int cap) {
    unsigned long long word = B[(size_t)r * NW + l];
    int pc = __popcll(word);
    int off = pc;
    for (int d = 1; d < 64; d <<= 1) {
        int n = __shfl_up(off, d);
        if (l >= d) off += n;
    }
    int total = __shfl(off, 63);
    int base = off - pc;
    while (word) {
        int b = (int)__ffsll(word) - 1;
        word &= word - 1;
        if (base < cap) cols[base] = l * 64 + b;
        ++base;
    }
    return total;
}

// ---------------- fused: column stats partials (blocks 0..63) + g bitmask (blocks 64..4159) ----
__global__ void k_pre(const float* __restrict__ h, const float* __restrict__ g,
                      double* __restrict__ psum, double* __restrict__ psq,
                      unsigned long long* __restrict__ B) {
    int blk = blockIdx.x;
    int t = threadIdx.x;   // 256
    if (blk < 64) {
        // ---- stats partials: rows [64*blk, 64*blk+64), thread = dim ----
        int d = t;
        int r0 = blk * 64;
        double s0=0,s1=0,s2=0,s3=0,q0=0,q1=0,q2=0,q3=0;
        for (int k = 0; k < 64; k += 4) {
            double x0 = (double)h[(size_t)(r0+k+0) * DD + d];
            double x1 = (double)h[(size_t)(r0+k+1) * DD + d];
            double x2 = (double)h[(size_t)(r0+k+2) * DD + d];
            double x3 = (double)h[(size_t)(r0+k+3) * DD + d];
            s0 += x0; q0 += x0*x0;
            s1 += x1; q1 += x1*x1;
            s2 += x2; q2 += x2*x2;
            s3 += x3; q3 += x3*x3;
        }
        psum[blk * DD + d] = (s0+s1)+(s2+s3);
        psq [blk * DD + d] = (q0+q1)+(q2+q3);
    } else {
        // ---- bitmask row i, dwordx4 loads + 16-lane shfl-xor assembly ----
        int i = blk - 64;
        int q = t >> 6, l = t & 63;
        const float4* g4 = (const float4*)(g + (size_t)i * NN);
        for (int wi = 0; wi < 4; ++wi) {
            float4 v = g4[q * 256 + wi * 64 + l];
            unsigned int nib = (unsigned int)(v.x != 0.f)
                             | ((unsigned int)(v.y != 0.f) << 1)
                             | ((unsigned int)(v.z != 0.f) << 2)
                             | ((unsigned int)(v.w != 0.f) << 3);
            unsigned long long word = (unsigned long long)nib << (4 * (l & 15));
            unsigned int lo = (unsigned int)word, hi = (unsigned int)(word >> 32);
            for (int s = 1; s < 16; s <<= 1) {
                lo |= __shfl_xor(lo, s, 16);
                hi |= __shfl_xor(hi, s, 16);
            }
            if ((l & 15) == 0)
                B[(size_t)i * NW + 16 * q + 4 * wi + (l >> 4)] =
                    ((unsigned long long)hi << 32) | lo;
        }
    }
}

// ---------------- stats final: 1 block x 1024 ----------------
__global__ void k_stats_final(const double* __restrict__ psum, const double* __restrict__ psq,
                              double* __restrict__ mu, double* __restrict__ rstd) {
    __shared__ double rs[4][DD];
    __shared__ double rq[4][DD];
    int t = threadIdx.x;
    int d = t & (DD - 1);
    int q = t >> 8;
    double s0=0,s1=0,q0=0,q1=0;
    int b0 = q * 16;
    for (int k = 0; k < 16; k += 2) {
        s0 += psum[(b0+k)   * DD + d];
        s1 += psum[(b0+k+1) * DD + d];
        q0 += psq [(b0+k)   * DD + d];
        q1 += psq [(b0+k+1) * DD + d];
    }
    rs[q][d] = s0 + s1;
    rq[q][d] = q0 + q1;
    __syncthreads();
    if (q == 0) {
        double S  = (rs[0][d]+rs[1][d]) + (rs[2][d]+rs[3][d]);
        double Q  = (rq[0][d]+rq[1][d]) + (rq[2][d]+rq[3][d]);
        double m  = S / (double)NN;
        double var = Q / (double)NN - m * m;
        mu[d]   = m;
        rstd[d] = 1.0 / sqrt(var + 1e-5);
    }
}

// ---------------- fused: norm+zpf (blocks 0..1023, wave-per-row) + twohop (1024..2047) ----------
__global__ void k_mid(const float* __restrict__ h, const double* __restrict__ mu,
                      const double* __restrict__ rstd, const float* __restrict__ gamma,
                      const float* __restrict__ beta, const float* __restrict__ w,
                      const float* __restrict__ bp, float* __restrict__ hn,
                      double* __restrict__ zpf, const unsigned long long* __restrict__ Bm,
                      unsigned long long* __restrict__ T) {
    __shared__ int cols[4][136];
    int blk = blockIdx.x;
    int t = threadIdx.x;
    int wv = t >> 6, l = t & 63;
    if (blk < 1024) {
        // ---- norm + zpf, wave per row ----
        int r = blk * 4 + wv;
        const float4*  h4  = (const float4*)h;
        const double2* mu2 = (const double2*)mu;
        const double2* rs2 = (const double2*)rstd;
        const float4*  ga4 = (const float4*)gamma;
        const float4*  be4 = (const float4*)beta;
        const float4*  w4  = (const float4*)w;
        float4 hv = h4[(size_t)r * 64 + l];
        double2 mA = mu2[2*l], mB = mu2[2*l+1];
        double2 rA = rs2[2*l], rB = rs2[2*l+1];
        float4 ga = ga4[l], be = be4[l], wl = w4[l];
        double h0 = ((double)hv.x - mA.x) * rA.x * (double)ga.x + (double)be.x;
        double h1 = ((double)hv.y - mA.y) * rA.y * (double)ga.y + (double)be.y;
        double h2 = ((double)hv.z - mB.x) * rB.x * (double)ga.z + (double)be.z;
        double h3 = ((double)hv.w - mB.y) * rB.y * (double)ga.w + (double)be.w;
        float4 o = { (float)h0, (float)h1, (float)h2, (float)h3 };
        ((float4*)hn)[(size_t)r * 64 + l] = o;
        double acc = (h0 * (double)wl.x + h1 * (double)wl.y)
                   + (h2 * (double)wl.z + h3 * (double)wl.w);
        for (int off = 32; off > 0; off >>= 1) acc += __shfl_down(acc, off);
        if (l == 0) zpf[r] = acc + (double)bp[0];
    } else {
        // ---- twohop, wave per row ----
        int r = (blk - 1024) * 4 + wv;
        int cnt = build_list(Bm, r, l, cols[wv], 128);
        if (cnt > 128) cnt = 128;
        unsigned long long a0 = 0ull, a1 = 0ull;
        int j = 0;
        for (; j + 1 < cnt; j += 2) {
            a0 |= Bm[(size_t)cols[wv][j]     * NW + l];
            a1 |= Bm[(size_t)cols[wv][j + 1] * NW + l];
        }
        if (j < cnt) a0 |= Bm[(size_t)cols[wv][j] * NW + l];
        T[(size_t)r * NW + l] = a0 | a1;
    }
}

// ---------------- agg, wave-per-row, float4 gather, fp64; emits Z1/Z3/degi ----------------
__global__ void k_agg(const float* __restrict__ h, const double* __restrict__ mu,
                      const double* __restrict__ rstd, const float* __restrict__ gamma,
                      const float* __restrict__ beta, const unsigned long long* __restrict__ Bm,
                      const float* __restrict__ w, const float* __restrict__ bp,
                      double* __restrict__ Z1, double* __restrict__ Z3,
                      int* __restrict__ degi) {
    __shared__ int cols[4][136];
    int t = threadIdx.x;
    int wv = t >> 6, l = t & 63;
    int r = blockIdx.x * 4 + wv;
    int cnt = build_list(Bm, r, l, cols[wv], 128);
    if (cnt > 128) cnt = 128;
    const float4* h4 = (const float4*)h;
    double s0=0,s1=0,s2=0,s3=0,u0=0,u1=0,u2=0,u3=0;
    int j = 0;
    for (; j + 1 < cnt; j += 2) {
        float4 v0 = h4[(size_t)cols[wv][j]     * 64 + l];
        float4 v1 = h4[(size_t)cols[wv][j + 1] * 64 + l];
        s0 += (double)v0.x; s1 += (double)v0.y; s2 += (double)v0.z; s3 += (double)v0.w;
        u0 += (double)v1.x; u1 += (double)v1.y; u2 += (double)v1.z; u3 += (double)v1.w;
    }
    if (j < cnt) {
        float4 v0 = h4[(size_t)cols[wv][j] * 64 + l];
        s0 += (double)v0.x; s1 += (double)v0.y; s2 += (double)v0.z; s3 += (double)v0.w;
    }
    s0 += u0; s1 += u1; s2 += u2; s3 += u3;
    const double2* mu2 = (const double2*)mu;
    const double2* rs2 = (const double2*)rstd;
    const float4*  ga4 = (const float4*)gamma;
    const float4*  be4 = (const float4*)beta;
    const float4*  w4  = (const float4*)w;
    double2 mA = mu2[2*l], mB = mu2[2*l+1];
    double2 rA = rs2[2*l], rB = rs2[2*l+1];
    float4 ga = ga4[l], be = be4[l], wl = w4[l];
    double inv = 1.0 / (double)cnt;
    double g0 = (s0 * inv - mA.x) * rA.x * (double)ga.x + (double)be.x;
    double g1 = (s1 * inv - mA.y) * rA.y * (double)ga.y + (double)be.y;
    double g2 = (s2 * inv - mB.x) * rB.x * (double)ga.z + (double)be.z;
    double g3 = (s3 * inv - mB.y) * rB.y * (double)ga.w + (double)be.w;
    float4 hv = h4[(size_t)r * 64 + l];
    double h0 = ((double)hv.x - mA.x) * rA.x * (double)ga.x + (double)be.x;
    double h1 = ((double)hv.y - mA.y) * rA.y * (double)ga.y + (double)be.y;
    double h2 = ((double)hv.z - mB.x) * rB.x * (double)ga.z + (double)be.z;
    double h3 = ((double)hv.w - mB.y) * rB.y * (double)ga.w + (double)be.w;
    double z1p = (fabs(h0 - g0) + fabs(h1 - g1)) + (fabs(h2 - g2) + fabs(h3 - g3));
    double z3p = (g0 * (double)wl.x + g1 * (double)wl.y)
               + (g2 * (double)wl.z + g3 * (double)wl.w);
    for (int off = 32; off > 0; off >>= 1) {
        z1p += __shfl_down(z1p, off);
        z3p += __shfl_down(z3p, off);
    }
    if (l == 0) { Z1[r] = z1p; Z3[r] = z3p + (double)bp[0]; degi[r] = cnt; }
}

// ---------------- scores: each of 16 blocks redundantly reduces softmax stats (deterministic) ----
__global__ void k_scorekeys(const double* __restrict__ Z1, const double* __restrict__ Z3,
                            const double* __restrict__ zpf, const int* __restrict__ degi,
                            const float* __restrict__ sigma1, float* __restrict__ scores,
                            unsigned long long* __restrict__ keys) {
    __shared__ double red[256];
    int t = threadIdx.x;
    double mx = -1e300;
    for (int k = 0; k < 16; ++k) mx = fmax(mx, Z3[t + 256 * k]);
    red[t] = mx;
    __syncthreads();
    for (int s = 128; s > 0; s >>= 1) {
        if (t < s) red[t] = fmax(red[t], red[t + s]);
        __syncthreads();
    }
    double M = red[0];
    __syncthreads();
    double se = 0.0;
    for (int k = 0; k < 16; ++k) se += exp(Z3[t + 256 * k] - M);
    red[t] = se;
    __syncthreads();
    for (int s = 128; s > 0; s >>= 1) {
        if (t < s) red[t] += red[t + s];
        __syncthreads();
    }
    double sum = red[0];
    int i = blockIdx.x * 256 + t;
    double s1 = (double)sigma1[0];
    double pg = exp(Z3[i] - M) / sum;
    double pl = 1.0 / (1.0 + exp(-(Z1[i] + (double)degi[i])));
    double pt = 1.0 / (1.0 + exp(-(pl + pg)));
    double pf = 1.0 / (1.0 + exp(-zpf[i]));
    float sc = (float)(s1 * pt + (1.0 - s1) * pf);
    scores[i] = sc;
    unsigned int b2 = __float_as_uint(sc);
    unsigned int ka = (b2 & 0x80000000u) ? ~b2 : (b2 ^ 0x80000000u);  // ascending order key
    keys[i] = ((unsigned long long)(~ka) << 32) | (unsigned int)i;    // asc = desc score, asc idx
}

// ---------------- rank-by-counting top-k scatter (no atomics) ----------------
__global__ void k_rank(const unsigned long long* __restrict__ keys, int* __restrict__ idx_int,
                       float* __restrict__ out_idx) {
    __shared__ unsigned long long Kl[NN];
    int t = threadIdx.x;
    for (int i = t; i < NN; i += 256) Kl[i] = keys[i];
    __syncthreads();
    int il = t >> 4, sub = t & 15;
    int i = blockIdx.x * 16 + il;
    unsigned long long ki = Kl[i];
    int c0 = 0, c1 = 0, c2 = 0, c3 = 0;
    for (int jj = 0; jj < 256; jj += 4) {
        int j = sub + (jj << 4);
        c0 += (Kl[j]      < ki) ? 1 : 0;
        c1 += (Kl[j + 16] < ki) ? 1 : 0;
        c2 += (Kl[j + 32] < ki) ? 1 : 0;
        c3 += (Kl[j + 48] < ki) ? 1 : 0;
    }
    int cnt = (c0 + c1) + (c2 + c3);
    for (int off = 8; off > 0; off >>= 1) cnt += __shfl_down(cnt, off, 16);
    if (sub == 0 && cnt < KK) {   // exact bijection: keys are unique
        idx_int[cnt] = i;
        out_idx[cnt] = (float)i;
    }
}

// ---------------- row sums: 32 blocks x 64 (single wave — no barriers); S rebuilt in LDS -------
__global__ void k_rowsum(const unsigned long long* __restrict__ T, const int* __restrict__ idx_int,
                         float* __restrict__ inv_rs) {
    __shared__ unsigned long long Sl[NW];
    int t = threadIdx.x;   // 64
    Sl[t] = 0ull;
    for (int j = t; j < KK; j += 64) {
        int ii = idx_int[j];
        atomicOr(&Sl[ii >> 6], 1ull << (ii & 63));
    }
    // single-wave block: LDS ops are program-ordered; no barrier needed
    int j = blockIdx.x * 64 + t;
    int r = idx_int[j];
    const unsigned long long* Tr = T + (size_t)r * NW;
    int c0 = 0, c1 = 0, c2 = 0, c3 = 0;
    for (int w = 0; w < NW; w += 4) {
        c0 += __popcll(Tr[w]     & Sl[w]);
        c1 += __popcll(Tr[w + 1] & Sl[w + 1]);
        c2 += __popcll(Tr[w + 2] & Sl[w + 2]);
        c3 += __popcll(Tr[w + 3] & Sl[w + 3]);
    }
    inv_rs[j] = 1.0f / (float)((c0 + c1) + (c2 + c3));
}

// ---------------- fused outputs: g_new (blocks 0..2047) + new_h (blocks 2048..4095) ----------
__global__ void k_out(const unsigned long long* __restrict__ T, const int* __restrict__ idx_int,
                      const float* __restrict__ inv_rs, const float* __restrict__ scores,
                      const float* __restrict__ hn, float* __restrict__ out_gnew,
                      float* __restrict__ out_newh) {
    __shared__ unsigned long long Tl[NW];
    __shared__ int cols[2048];
    __shared__ int s_cnt;
    __shared__ float4 red[4][64];
    int blk = blockIdx.x;
    int t = threadIdx.x;   // 256
    if (blk < KK) {
        // ---- g_new row ----
        int r = blk;
        if (t < NW) Tl[t] = T[(size_t)idx_int[r] * NW + t];
        __syncthreads();
        const int4*   idx4 = (const int4*)idx_int;
        const float4* irs4 = (const float4*)inv_rs;
        float4* out4 = (float4*)(out_gnew + (size_t)r * KK);
        for (int c4 = t; c4 < KK / 4; c4 += 256) {
            int4 jc = idx4[c4];
            float4 iv = irs4[c4];
            float4 o;
            o.x = ((Tl[jc.x >> 6] >> (jc.x & 63)) & 1ull) ? iv.x : 0.0f;
            o.y = ((Tl[jc.y >> 6] >> (jc.y & 63)) & 1ull) ? iv.y : 0.0f;
            o.z = ((Tl[jc.z >> 6] >> (jc.z & 63)) & 1ull) ? iv.z : 0.0f;
            o.w = ((Tl[jc.w >> 6] >> (jc.w & 63)) & 1ull) ? iv.w : 0.0f;
            out4[c4] = o;
        }
    } else {
        // ---- new_h row: 4-wave float4 gather of hn with fused score scaling ----
        int r = blk - KK;
        int wv = t >> 6, l = t & 63;
        if (t < 64) {
            int total = build_list(T, idx_int[r], t, cols, 2048);
            if (t == 63) s_cnt = total;
        }
        __syncthreads();
        int cnt = s_cnt < 2048 ? s_cnt : 2048;
        const float4* hn4 = (const float4*)hn;
        float4 a0 = {0,0,0,0}, a1 = {0,0,0,0};
        int j = wv;
        for (; j + 4 < cnt; j += 8) {
            int c0 = cols[j], c1 = cols[j + 4];
            float s0 = scores[c0], s1 = scores[c1];
            float4 v0 = hn4[(size_t)c0 * 64 + l];
            float4 v1 = hn4[(size_t)c1 * 64 + l];
            a0.x = fmaf(s0, v0.x, a0.x); a0.y = fmaf(s0, v0.y, a0.y);
            a0.z = fmaf(s0, v0.z, a0.z); a0.w = fmaf(s0, v0.w, a0.w);
            a1.x = fmaf(s1, v1.x, a1.x); a1.y = fmaf(s1, v1.y, a1.y);
            a1.z = fmaf(s1, v1.z, a1.z); a1.w = fmaf(s1, v1.w, a1.w);
        }
        for (; j < cnt; j += 4) {
            int c0 = cols[j];
            float s0 = scores[c0];
            float4 v0 = hn4[(size_t)c0 * 64 + l];
            a0.x = fmaf(s0, v0.x, a0.x); a0.y = fmaf(s0, v0.y, a0.y);
            a0.z = fmaf(s0, v0.z, a0.z); a0.w = fmaf(s0, v0.w, a0.w);
        }
        float4 acc;
        acc.x = a0.x + a1.x; acc.y = a0.y + a1.y;
        acc.z = a0.z + a1.z; acc.w = a0.w + a1.w;
        red[wv][l] = acc;
        __syncthreads();
        if (t < 64) {
            float4 r0 = red[0][t], r1 = red[1][t], r2 = red[2][t], r3 = red[3][t];
            float4 o;
            o.x = (r0.x + r1.x) + (r2.x + r3.x);
            o.y = (r0.y + r1.y) + (r2.y + r3.y);
            o.z = (r0.z + r1.z) + (r2.z + r3.z);
            o.w = (r0.w + r1.w) + (r2.w + r3.w);
            ((float4*)(out_newh + (size_t)r * DD))[t] = o;
        }
    }
}

extern "C" void kernel_launch(void* const* d_in, const int* in_sizes, int n_in,
                              void* d_out, int out_size, void* d_ws, size_t ws_size,
                              hipStream_t stream) {
    const float* g      = (const float*)d_in[0];
    const float* h      = (const float*)d_in[1];
    const float* gamma  = (const float*)d_in[2];
    const float* beta   = (const float*)d_in[3];
    const float* w_proj = (const float*)d_in[4];
    const float* b_proj = (const float*)d_in[5];
    const float* sigma1 = (const float*)d_in[6];

    char* p = (char*)d_ws;
    auto alloc = [&](size_t bytes) -> void* {
        void* q = (void*)p;
        p += (bytes + 255) & ~(size_t)255;
        return q;
    };
    double* mu      = (double*)alloc(DD * 8);
    double* rstd    = (double*)alloc(DD * 8);
    double* psum    = (double*)alloc(64 * DD * 8);
    double* psq     = (double*)alloc(64 * DD * 8);
    double* zpf     = (double*)alloc(NN * 8);
    double* Z1      = (double*)alloc(NN * 8);
    double* Z3      = (double*)alloc(NN * 8);
    int*    degi    = (int*)alloc(NN * 4);
    float*  scores  = (float*)alloc(NN * 4);
    unsigned long long* keys = (unsigned long long*)alloc(NN * 8);
    int*    idx_int = (int*)alloc(KK * 4);
    float*  inv_rs  = (float*)alloc(KK * 4);
    unsigned long long* B = (unsigned long long*)alloc((size_t)NN * NW * 8);
    unsigned long long* T = (unsigned long long*)alloc((size_t)NN * NW * 8);
    float*  hn      = (float*)alloc((size_t)NN * DD * 4);

    float* out_gnew = (float*)d_out;                       // KK*KK
    float* out_newh = out_gnew + (size_t)KK * KK;          // KK*DD
    float* out_idx  = out_newh + (size_t)KK * DD;          // KK

    hipLaunchKernelGGL(k_pre,         dim3(64 + NN), dim3(256),  0, stream, h, g, psum, psq, B);
    hipLaunchKernelGGL(k_stats_final, dim3(1),       dim3(1024), 0, stream, psum, psq, mu, rstd);
    hipLaunchKernelGGL(k_mid,         dim3(2048),    dim3(256),  0, stream, h, mu, rstd, gamma, beta, w_proj, b_proj, hn, zpf, B, T);
    hipLaunchKernelGGL(k_agg,         dim3(1024),    dim3(256),  0, stream, h, mu, rstd, gamma, beta, B, w_proj, b_proj, Z1, Z3, degi);
    hipLaunchKernelGGL(k_scorekeys,   dim3(16),      dim3(256),  0, stream, Z1, Z3, zpf, degi, sigma1, scores, keys);
    hipLaunchKernelGGL(k_rank,        dim3(256),     dim3(256),  0, stream, keys, idx_int, out_idx);
    hipLaunchKernelGGL(k_rowsum,      dim3(32),      dim3(64),   0, stream, T, idx_int, inv_rs);
    hipLaunchKernelGGL(k_out,         dim3(2 * KK),  dim3(256),  0, stream, T, idx_int, inv_rs, scores, hn, out_gnew, out_newh);
}

// Round 6
// 179.714 us; speedup vs baseline: 1.9425x; 1.0318x over previous
//
#include <hip/hip_runtime.h>
#include <math.h>

#define NN 4096
#define DD 256
#define KK 2048
#define NW 64   // u64 words per bitmask row

// Build sorted column list for bitmask row r into LDS `cols` (one wave, lane l).
// Returns total bit count. List is ascending.
__device__ __forceinline__ int build_list(const unsigned long long* __restrict__ B, int r,
                                          int l, int* cols, int cap) {
    unsigned long long word = B[(size_t)r * NW + l];
    int pc = __popcll(word);
    int off = pc;
    for (int d = 1; d < 64; d <<= 1) {
        int n = __shfl_up(off, d);
        if (l >= d) off += n;
    }
    int total = __shfl(off, 63);
    int base = off - pc;
    while (word) {
        int b = (int)__ffsll(word) - 1;
        word &= word - 1;
        if (base < cap) cols[base] = l * 64 + b;
        ++base;
    }
    return total;
}

// ---------------- fused: column stats partials (blocks 0..63) + g bitmask (blocks 64..4159) ----
__global__ void k_pre(const float* __restrict__ h, const float* __restrict__ g,
                      double* __restrict__ psum, double* __restrict__ psq,
                      unsigned long long* __restrict__ B) {
    int blk = blockIdx.x;
    int t = threadIdx.x;   // 256
    if (blk < 64) {
        int d = t;
        int r0 = blk * 64;
        double s0=0,s1=0,s2=0,s3=0,q0=0,q1=0,q2=0,q3=0;
        for (int k = 0; k < 64; k += 4) {
            double x0 = (double)h[(size_t)(r0+k+0) * DD + d];
            double x1 = (double)h[(size_t)(r0+k+1) * DD + d];
            double x2 = (double)h[(size_t)(r0+k+2) * DD + d];
            double x3 = (double)h[(size_t)(r0+k+3) * DD + d];
            s0 += x0; q0 += x0*x0;
            s1 += x1; q1 += x1*x1;
            s2 += x2; q2 += x2*x2;
            s3 += x3; q3 += x3*x3;
        }
        psum[blk * DD + d] = (s0+s1)+(s2+s3);
        psq [blk * DD + d] = (q0+q1)+(q2+q3);
    } else {
        int i = blk - 64;
        int q = t >> 6, l = t & 63;
        const float4* g4 = (const float4*)(g + (size_t)i * NN);
        for (int wi = 0; wi < 4; ++wi) {
            float4 v = g4[q * 256 + wi * 64 + l];
            unsigned int nib = (unsigned int)(v.x != 0.f)
                             | ((unsigned int)(v.y != 0.f) << 1)
                             | ((unsigned int)(v.z != 0.f) << 2)
                             | ((unsigned int)(v.w != 0.f) << 3);
            unsigned long long word = (unsigned long long)nib << (4 * (l & 15));
            unsigned int lo = (unsigned int)word, hi = (unsigned int)(word >> 32);
            for (int s = 1; s < 16; s <<= 1) {
                lo |= __shfl_xor(lo, s, 16);
                hi |= __shfl_xor(hi, s, 16);
            }
            if ((l & 15) == 0)
                B[(size_t)i * NW + 16 * q + 4 * wi + (l >> 4)] =
                    ((unsigned long long)hi << 32) | lo;
        }
    }
}

// ---------------- stats final: 1 block x 1024 ----------------
__global__ void k_stats_final(const double* __restrict__ psum, const double* __restrict__ psq,
                              double* __restrict__ mu, double* __restrict__ rstd) {
    __shared__ double rs[4][DD];
    __shared__ double rq[4][DD];
    int t = threadIdx.x;
    int d = t & (DD - 1);
    int q = t >> 8;
    double s0=0,s1=0,q0=0,q1=0;
    int b0 = q * 16;
    for (int k = 0; k < 16; k += 2) {
        s0 += psum[(b0+k)   * DD + d];
        s1 += psum[(b0+k+1) * DD + d];
        q0 += psq [(b0+k)   * DD + d];
        q1 += psq [(b0+k+1) * DD + d];
    }
    rs[q][d] = s0 + s1;
    rq[q][d] = q0 + q1;
    __syncthreads();
    if (q == 0) {
        double S  = (rs[0][d]+rs[1][d]) + (rs[2][d]+rs[3][d]);
        double Q  = (rq[0][d]+rq[1][d]) + (rq[2][d]+rq[3][d]);
        double m  = S / (double)NN;
        double var = Q / (double)NN - m * m;
        mu[d]   = m;
        rstd[d] = 1.0 / sqrt(var + 1e-5);
    }
}

// ---- fused main: blocks 0..1023 = agg+norm+zpf (wave-per-row); 1024..2047 = twohop -----------
__global__ void k_main(const float* __restrict__ h, const double* __restrict__ mu,
                       const double* __restrict__ rstd, const float* __restrict__ gamma,
                       const float* __restrict__ beta, const unsigned long long* __restrict__ Bm,
                       const float* __restrict__ w, const float* __restrict__ bp,
                       float* __restrict__ hn, double* __restrict__ zpf,
                       unsigned long long* __restrict__ T, double* __restrict__ Z1,
                       double* __restrict__ Z3, int* __restrict__ degi) {
    __shared__ int cols[4][136];
    int blk = blockIdx.x;
    int t = threadIdx.x;
    int wv = t >> 6, l = t & 63;
    if (blk < 1024) {
        int r = blk * 4 + wv;
        int cnt = build_list(Bm, r, l, cols[wv], 128);
        if (cnt > 128) cnt = 128;
        const float4* h4 = (const float4*)h;
        double s0=0,s1=0,s2=0,s3=0,u0=0,u1=0,u2=0,u3=0;
        int j = 0;
        for (; j + 1 < cnt; j += 2) {
            float4 v0 = h4[(size_t)cols[wv][j]     * 64 + l];
            float4 v1 = h4[(size_t)cols[wv][j + 1] * 64 + l];
            s0 += (double)v0.x; s1 += (double)v0.y; s2 += (double)v0.z; s3 += (double)v0.w;
            u0 += (double)v1.x; u1 += (double)v1.y; u2 += (double)v1.z; u3 += (double)v1.w;
        }
        if (j < cnt) {
            float4 v0 = h4[(size_t)cols[wv][j] * 64 + l];
            s0 += (double)v0.x; s1 += (double)v0.y; s2 += (double)v0.z; s3 += (double)v0.w;
        }
        s0 += u0; s1 += u1; s2 += u2; s3 += u3;
        const double2* mu2 = (const double2*)mu;
        const double2* rs2 = (const double2*)rstd;
        const float4*  ga4 = (const float4*)gamma;
        const float4*  be4 = (const float4*)beta;
        const float4*  w4  = (const float4*)w;
        double2 mA = mu2[2*l], mB = mu2[2*l+1];
        double2 rA = rs2[2*l], rB = rs2[2*l+1];
        float4 ga = ga4[l], be = be4[l], wl = w4[l];
        double inv = 1.0 / (double)cnt;
        double g0 = (s0 * inv - mA.x) * rA.x * (double)ga.x + (double)be.x;
        double g1 = (s1 * inv - mA.y) * rA.y * (double)ga.y + (double)be.y;
        double g2 = (s2 * inv - mB.x) * rB.x * (double)ga.z + (double)be.z;
        double g3 = (s3 * inv - mB.y) * rB.y * (double)ga.w + (double)be.w;
        float4 hv = h4[(size_t)r * 64 + l];
        double h0 = ((double)hv.x - mA.x) * rA.x * (double)ga.x + (double)be.x;
        double h1 = ((double)hv.y - mA.y) * rA.y * (double)ga.y + (double)be.y;
        double h2 = ((double)hv.z - mB.x) * rB.x * (double)ga.z + (double)be.z;
        double h3 = ((double)hv.w - mB.y) * rB.y * (double)ga.w + (double)be.w;
        // normalized row (fp32) for the output path
        float4 o = { (float)h0, (float)h1, (float)h2, (float)h3 };
        ((float4*)hn)[(size_t)r * 64 + l] = o;
        double z1p = (fabs(h0 - g0) + fabs(h1 - g1)) + (fabs(h2 - g2) + fabs(h3 - g3));
        double z3p = (g0 * (double)wl.x + g1 * (double)wl.y)
                   + (g2 * (double)wl.z + g3 * (double)wl.w);
        double zfp = (h0 * (double)wl.x + h1 * (double)wl.y)
                   + (h2 * (double)wl.z + h3 * (double)wl.w);
        for (int off = 32; off > 0; off >>= 1) {
            z1p += __shfl_down(z1p, off);
            z3p += __shfl_down(z3p, off);
            zfp += __shfl_down(zfp, off);
        }
        if (l == 0) {
            Z1[r] = z1p;
            Z3[r] = z3p + (double)bp[0];
            zpf[r] = zfp + (double)bp[0];
            degi[r] = cnt;
        }
    } else {
        // ---- twohop, wave per row ----
        int r = (blk - 1024) * 4 + wv;
        int cnt = build_list(Bm, r, l, cols[wv], 128);
        if (cnt > 128) cnt = 128;
        unsigned long long a0 = 0ull, a1 = 0ull;
        int j = 0;
        for (; j + 1 < cnt; j += 2) {
            a0 |= Bm[(size_t)cols[wv][j]     * NW + l];
            a1 |= Bm[(size_t)cols[wv][j + 1] * NW + l];
        }
        if (j < cnt) a0 |= Bm[(size_t)cols[wv][j] * NW + l];
        T[(size_t)r * NW + l] = a0 | a1;
    }
}

// ---------------- scores: each of 16 blocks redundantly reduces softmax stats (deterministic) ----
__global__ void k_scorekeys(const double* __restrict__ Z1, const double* __restrict__ Z3,
                            const double* __restrict__ zpf, const int* __restrict__ degi,
                            const float* __restrict__ sigma1, float* __restrict__ scores,
                            unsigned long long* __restrict__ keys) {
    __shared__ double red[256];
    int t = threadIdx.x;
    double mx = -1e300;
    for (int k = 0; k < 16; ++k) mx = fmax(mx, Z3[t + 256 * k]);
    red[t] = mx;
    __syncthreads();
    for (int s = 128; s > 0; s >>= 1) {
        if (t < s) red[t] = fmax(red[t], red[t + s]);
        __syncthreads();
    }
    double M = red[0];
    __syncthreads();
    double se = 0.0;
    for (int k = 0; k < 16; ++k) se += exp(Z3[t + 256 * k] - M);
    red[t] = se;
    __syncthreads();
    for (int s = 128; s > 0; s >>= 1) {
        if (t < s) red[t] += red[t + s];
        __syncthreads();
    }
    double sum = red[0];
    int i = blockIdx.x * 256 + t;
    double s1 = (double)sigma1[0];
    double pg = exp(Z3[i] - M) / sum;
    double pl = 1.0 / (1.0 + exp(-(Z1[i] + (double)degi[i])));
    double pt = 1.0 / (1.0 + exp(-(pl + pg)));
    double pf = 1.0 / (1.0 + exp(-zpf[i]));
    float sc = (float)(s1 * pt + (1.0 - s1) * pf);
    scores[i] = sc;
    unsigned int b2 = __float_as_uint(sc);
    unsigned int ka = (b2 & 0x80000000u) ? ~b2 : (b2 ^ 0x80000000u);  // ascending order key
    keys[i] = ((unsigned long long)(~ka) << 32) | (unsigned int)i;    // asc = desc score, asc idx
}

// ---------------- rank-by-counting top-k scatter (no atomics) ----------------
__global__ void k_rank(const unsigned long long* __restrict__ keys, int* __restrict__ idx_int,
                       float* __restrict__ out_idx) {
    __shared__ unsigned long long Kl[NN];
    int t = threadIdx.x;
    for (int i = t; i < NN; i += 256) Kl[i] = keys[i];
    __syncthreads();
    int il = t >> 4, sub = t & 15;
    int i = blockIdx.x * 16 + il;
    unsigned long long ki = Kl[i];
    int c0 = 0, c1 = 0, c2 = 0, c3 = 0;
    for (int jj = 0; jj < 256; jj += 4) {
        int j = sub + (jj << 4);
        c0 += (Kl[j]      < ki) ? 1 : 0;
        c1 += (Kl[j + 16] < ki) ? 1 : 0;
        c2 += (Kl[j + 32] < ki) ? 1 : 0;
        c3 += (Kl[j + 48] < ki) ? 1 : 0;
    }
    int cnt = (c0 + c1) + (c2 + c3);
    for (int off = 8; off > 0; off >>= 1) cnt += __shfl_down(cnt, off, 16);
    if (sub == 0 && cnt < KK) {   // exact bijection: keys are unique
        idx_int[cnt] = i;
        out_idx[cnt] = (float)i;
    }
}

// ---------------- row sums: 32 blocks x 64 (single wave — no barriers); S rebuilt in LDS -------
__global__ void k_rowsum(const unsigned long long* __restrict__ T, const int* __restrict__ idx_int,
                         float* __restrict__ inv_rs) {
    __shared__ unsigned long long Sl[NW];
    int t = threadIdx.x;   // 64
    Sl[t] = 0ull;
    for (int j = t; j < KK; j += 64) {
        int ii = idx_int[j];
        atomicOr(&Sl[ii >> 6], 1ull << (ii & 63));
    }
    // single-wave block: LDS ops are program-ordered; no barrier needed
    int j = blockIdx.x * 64 + t;
    int r = idx_int[j];
    const unsigned long long* Tr = T + (size_t)r * NW;
    int c0 = 0, c1 = 0, c2 = 0, c3 = 0;
    for (int w = 0; w < NW; w += 4) {
        c0 += __popcll(Tr[w]     & Sl[w]);
        c1 += __popcll(Tr[w + 1] & Sl[w + 1]);
        c2 += __popcll(Tr[w + 2] & Sl[w + 2]);
        c3 += __popcll(Tr[w + 3] & Sl[w + 3]);
    }
    inv_rs[j] = 1.0f / (float)((c0 + c1) + (c2 + c3));
}

// ---------------- fused outputs: g_new (blocks 0..2047) + new_h (blocks 2048..4095) ----------
__global__ void k_out(const unsigned long long* __restrict__ T, const int* __restrict__ idx_int,
                      const float* __restrict__ inv_rs, const float* __restrict__ scores,
                      const float* __restrict__ hn, float* __restrict__ out_gnew,
                      float* __restrict__ out_newh) {
    __shared__ unsigned long long Tl[NW];
    __shared__ int cols[2048];
    __shared__ int s_cnt;
    __shared__ float4 red[4][64];
    int blk = blockIdx.x;
    int t = threadIdx.x;   // 256
    if (blk < KK) {
        // ---- g_new row ----
        int r = blk;
        if (t < NW) Tl[t] = T[(size_t)idx_int[r] * NW + t];
        __syncthreads();
        const int4*   idx4 = (const int4*)idx_int;
        const float4* irs4 = (const float4*)inv_rs;
        float4* out4 = (float4*)(out_gnew + (size_t)r * KK);
        for (int c4 = t; c4 < KK / 4; c4 += 256) {
            int4 jc = idx4[c4];
            float4 iv = irs4[c4];
            float4 o;
            o.x = ((Tl[jc.x >> 6] >> (jc.x & 63)) & 1ull) ? iv.x : 0.0f;
            o.y = ((Tl[jc.y >> 6] >> (jc.y & 63)) & 1ull) ? iv.y : 0.0f;
            o.z = ((Tl[jc.z >> 6] >> (jc.z & 63)) & 1ull) ? iv.z : 0.0f;
            o.w = ((Tl[jc.w >> 6] >> (jc.w & 63)) & 1ull) ? iv.w : 0.0f;
            out4[c4] = o;
        }
    } else {
        // ---- new_h row: 4-wave float4 gather, 4-deep ILP, fused score scaling ----
        int r = blk - KK;
        int wv = t >> 6, l = t & 63;
        if (t < 64) {
            int total = build_list(T, idx_int[r], t, cols, 2048);
            if (t == 63) s_cnt = total;
        }
        __syncthreads();
        int cnt = s_cnt < 2048 ? s_cnt : 2048;
        const float4* hn4 = (const float4*)hn;
        float4 a0 = {0,0,0,0}, a1 = {0,0,0,0}, a2 = {0,0,0,0}, a3 = {0,0,0,0};
        int j = wv;
        for (; j + 12 < cnt; j += 16) {
            int c0 = cols[j], c1 = cols[j + 4], c2 = cols[j + 8], c3 = cols[j + 12];
            float s0 = scores[c0], s1 = scores[c1], s2 = scores[c2], s3 = scores[c3];
            float4 v0 = hn4[(size_t)c0 * 64 + l];
            float4 v1 = hn4[(size_t)c1 * 64 + l];
            float4 v2 = hn4[(size_t)c2 * 64 + l];
            float4 v3 = hn4[(size_t)c3 * 64 + l];
            a0.x = fmaf(s0, v0.x, a0.x); a0.y = fmaf(s0, v0.y, a0.y);
            a0.z = fmaf(s0, v0.z, a0.z); a0.w = fmaf(s0, v0.w, a0.w);
            a1.x = fmaf(s1, v1.x, a1.x); a1.y = fmaf(s1, v1.y, a1.y);
            a1.z = fmaf(s1, v1.z, a1.z); a1.w = fmaf(s1, v1.w, a1.w);
            a2.x = fmaf(s2, v2.x, a2.x); a2.y = fmaf(s2, v2.y, a2.y);
            a2.z = fmaf(s2, v2.z, a2.z); a2.w = fmaf(s2, v2.w, a2.w);
            a3.x = fmaf(s3, v3.x, a3.x); a3.y = fmaf(s3, v3.y, a3.y);
            a3.z = fmaf(s3, v3.z, a3.z); a3.w = fmaf(s3, v3.w, a3.w);
        }
        for (; j < cnt; j += 4) {
            int c0 = cols[j];
            float s0 = scores[c0];
            float4 v0 = hn4[(size_t)c0 * 64 + l];
            a0.x = fmaf(s0, v0.x, a0.x); a0.y = fmaf(s0, v0.y, a0.y);
            a0.z = fmaf(s0, v0.z, a0.z); a0.w = fmaf(s0, v0.w, a0.w);
        }
        float4 acc;
        acc.x = (a0.x + a1.x) + (a2.x + a3.x);
        acc.y = (a0.y + a1.y) + (a2.y + a3.y);
        acc.z = (a0.z + a1.z) + (a2.z + a3.z);
        acc.w = (a0.w + a1.w) + (a2.w + a3.w);
        red[wv][l] = acc;
        __syncthreads();
        if (t < 64) {
            float4 r0 = red[0][t], r1 = red[1][t], r2 = red[2][t], r3 = red[3][t];
            float4 o;
            o.x = (r0.x + r1.x) + (r2.x + r3.x);
            o.y = (r0.y + r1.y) + (r2.y + r3.y);
            o.z = (r0.z + r1.z) + (r2.z + r3.z);
            o.w = (r0.w + r1.w) + (r2.w + r3.w);
            ((float4*)(out_newh + (size_t)r * DD))[t] = o;
        }
    }
}

extern "C" void kernel_launch(void* const* d_in, const int* in_sizes, int n_in,
                              void* d_out, int out_size, void* d_ws, size_t ws_size,
                              hipStream_t stream) {
    const float* g      = (const float*)d_in[0];
    const float* h      = (const float*)d_in[1];
    const float* gamma  = (const float*)d_in[2];
    const float* beta   = (const float*)d_in[3];
    const float* w_proj = (const float*)d_in[4];
    const float* b_proj = (const float*)d_in[5];
    const float* sigma1 = (const float*)d_in[6];

    char* p = (char*)d_ws;
    auto alloc = [&](size_t bytes) -> void* {
        void* q = (void*)p;
        p += (bytes + 255) & ~(size_t)255;
        return q;
    };
    double* mu      = (double*)alloc(DD * 8);
    double* rstd    = (double*)alloc(DD * 8);
    double* psum    = (double*)alloc(64 * DD * 8);
    double* psq     = (double*)alloc(64 * DD * 8);
    double* zpf     = (double*)alloc(NN * 8);
    double* Z1      = (double*)alloc(NN * 8);
    double* Z3      = (double*)alloc(NN * 8);
    int*    degi    = (int*)alloc(NN * 4);
    float*  scores  = (float*)alloc(NN * 4);
    unsigned long long* keys = (unsigned long long*)alloc(NN * 8);
    int*    idx_int = (int*)alloc(KK * 4);
    float*  inv_rs  = (float*)alloc(KK * 4);
    unsigned long long* B = (unsigned long long*)alloc((size_t)NN * NW * 8);
    unsigned long long* T = (unsigned long long*)alloc((size_t)NN * NW * 8);
    float*  hn      = (float*)alloc((size_t)NN * DD * 4);

    float* out_gnew = (float*)d_out;                       // KK*KK
    float* out_newh = out_gnew + (size_t)KK * KK;          // KK*DD
    float* out_idx  = out_newh + (size_t)KK * DD;          // KK

    hipLaunchKernelGGL(k_pre,         dim3(64 + NN), dim3(256),  0, stream, h, g, psum, psq, B);
    hipLaunchKernelGGL(k_stats_final, dim3(1),       dim3(1024), 0, stream, psum, psq, mu, rstd);
    hipLaunchKernelGGL(k_main,        dim3(2048),    dim3(256),  0, stream, h, mu, rstd, gamma, beta, B, w_proj, b_proj, hn, zpf, T, Z1, Z3, degi);
    hipLaunchKernelGGL(k_scorekeys,   dim3(16),      dim3(256),  0, stream, Z1, Z3, zpf, degi, sigma1, scores, keys);
    hipLaunchKernelGGL(k_rank,        dim3(256),     dim3(256),  0, stream, keys, idx_int, out_idx);
    hipLaunchKernelGGL(k_rowsum,      dim3(32),      dim3(64),   0, stream, T, idx_int, inv_rs);
    hipLaunchKernelGGL(k_out,         dim3(2 * KK),  dim3(256),  0, stream, T, idx_int, inv_rs, scores, hn, out_gnew, out_newh);
}